// Round 10
// baseline (578.204 us; speedup 1.0000x reference)
//
#include <hip/hip_runtime.h>
#include <math.h>

#define NN    16384
#define NE    262144
#define NHEAD 4
#define HC    512
#define NG    8

typedef __bf16 bf16x8 __attribute__((ext_vector_type(8)));
typedef float floatx4 __attribute__((ext_vector_type(4)));

__device__ __forceinline__ unsigned short f2bf(float f) {
    union { float f; unsigned u; } v{f};
    unsigned r = v.u + 0x7FFFu + ((v.u >> 16) & 1u);  // RNE
    return (unsigned short)(r >> 16);
}

__device__ __forceinline__ void unpk8(uint4 v, float* f) {
    f[0] = __uint_as_float(v.x << 16); f[1] = __uint_as_float(v.x & 0xFFFF0000u);
    f[2] = __uint_as_float(v.y << 16); f[3] = __uint_as_float(v.y & 0xFFFF0000u);
    f[4] = __uint_as_float(v.z << 16); f[5] = __uint_as_float(v.z & 0xFFFF0000u);
    f[6] = __uint_as_float(v.w << 16); f[7] = __uint_as_float(v.w & 0xFFFF0000u);
}

// async 16B global->LDS (lds dest is wave-uniform base; lane i lands at base+i*16)
__device__ __forceinline__ void gl_lds16(const unsigned short* g, unsigned short* l) {
    __builtin_amdgcn_global_load_lds(
        (const __attribute__((address_space(1))) unsigned int*)g,
        (__attribute__((address_space(3))) unsigned int*)l, 16, 0, 0);
}

// ---------- CSR build ----------
__global__ void k_hist(const int* __restrict__ dst, int* __restrict__ cnt) {
    int e = blockIdx.x * 256 + threadIdx.x;
    if (e < NE) atomicAdd(&cnt[dst[e]], 1);
}

__global__ __launch_bounds__(1024) void k_scan(const int* __restrict__ cnt,
                                               int* __restrict__ rp,
                                               int* __restrict__ offp,
                                               const int* __restrict__ batch,
                                               int* __restrict__ gcnt) {
    __shared__ int part[1024];
    int t = threadIdx.x;
    // fused k_gcnt: batch sorted -> counts via binary searches (threads 0..7)
    if (t < NG) {
        int lb[2];
#pragma unroll
        for (int q = 0; q < 2; q++) {
            int target = t + q;
            int lo = 0, hi = NN;
            while (lo < hi) {
                int mid = (lo + hi) >> 1;
                if (batch[mid] < target) lo = mid + 1; else hi = mid;
            }
            lb[q] = lo;
        }
        gcnt[t] = lb[1] - lb[0];
    }
    int base = t * 16;
    int loc[16];
    int s = 0;
#pragma unroll
    for (int i = 0; i < 16; i++) { loc[i] = s; s += cnt[base + i]; }
    part[t] = s;
    __syncthreads();
    for (int off = 1; off < 1024; off <<= 1) {
        int v = 0;
        if (t >= off) v = part[t - off];
        __syncthreads();
        if (t >= off) part[t] += v;
        __syncthreads();
    }
    int excl = (t == 0) ? 0 : part[t - 1];
#pragma unroll
    for (int i = 0; i < 16; i++) {
        int r = excl + loc[i];
        rp[base + i] = r;
        offp[base + i] = r;
    }
    if (t == 1023) rp[NN] = excl + s;
}

// scatter src + edge_attr directly into CSR slots
__global__ void k_fill(const int* __restrict__ dst, const int* __restrict__ src,
                       const float* __restrict__ ea, int* __restrict__ offp,
                       int* __restrict__ csrc, float2* __restrict__ ce) {
    int e = blockIdx.x * 256 + threadIdx.x;
    if (e < NE) {
        int d = dst[e];
        int pos = atomicAdd(&offp[d], 1);
        csrc[pos] = src[e];
        ce[pos] = *(const float2*)(ea + 2 * (size_t)e);
    }
}

// ---------- layer-1 linear (K=5), bf16 out, vectorized ----------
__global__ __launch_bounds__(256) void k_lin1(const float* __restrict__ x,
                                              const float* __restrict__ Wl,
                                              const float* __restrict__ Wr,
                                              unsigned short* __restrict__ xl,
                                              unsigned short* __restrict__ xr) {
    int n = blockIdx.x * 4 + (threadIdx.x >> 6);
    int lane = threadIdx.x & 63;
    int j0 = lane << 3;
    float xs[5];
#pragma unroll
    for (int k = 0; k < 5; k++) xs[k] = x[n * 5 + k];
    float al[8] = {}, ar[8] = {};
#pragma unroll
    for (int k = 0; k < 5; k++) {
        float4 wl0 = *(const float4*)(Wl + k * 512 + j0);
        float4 wl1 = *(const float4*)(Wl + k * 512 + j0 + 4);
        float4 wr0 = *(const float4*)(Wr + k * 512 + j0);
        float4 wr1 = *(const float4*)(Wr + k * 512 + j0 + 4);
        al[0] += xs[k] * wl0.x; al[1] += xs[k] * wl0.y; al[2] += xs[k] * wl0.z; al[3] += xs[k] * wl0.w;
        al[4] += xs[k] * wl1.x; al[5] += xs[k] * wl1.y; al[6] += xs[k] * wl1.z; al[7] += xs[k] * wl1.w;
        ar[0] += xs[k] * wr0.x; ar[1] += xs[k] * wr0.y; ar[2] += xs[k] * wr0.z; ar[3] += xs[k] * wr0.w;
        ar[4] += xs[k] * wr1.x; ar[5] += xs[k] * wr1.y; ar[6] += xs[k] * wr1.z; ar[7] += xs[k] * wr1.w;
    }
    ushort4 o0, o1;
    o0.x = f2bf(al[0]); o0.y = f2bf(al[1]); o0.z = f2bf(al[2]); o0.w = f2bf(al[3]);
    o1.x = f2bf(al[4]); o1.y = f2bf(al[5]); o1.z = f2bf(al[6]); o1.w = f2bf(al[7]);
    *(ushort4*)(xl + (size_t)n * 512 + j0) = o0;
    *(ushort4*)(xl + (size_t)n * 512 + j0 + 4) = o1;
    o0.x = f2bf(ar[0]); o0.y = f2bf(ar[1]); o0.z = f2bf(ar[2]); o0.w = f2bf(ar[3]);
    o1.x = f2bf(ar[4]); o1.y = f2bf(ar[5]); o1.z = f2bf(ar[6]); o1.w = f2bf(ar[7]);
    *(ushort4*)(xr + (size_t)n * 512 + j0) = o0;
    *(ushort4*)(xr + (size_t)n * 512 + j0 + 4) = o1;
}

// ---------- 4 weight transposes in one dispatch ----------
__global__ __launch_bounds__(256) void k_wt4(const float* __restrict__ W0,
                                             const float* __restrict__ W1,
                                             const float* __restrict__ W2,
                                             const float* __restrict__ W3,
                                             unsigned short* __restrict__ Wt2,
                                             unsigned short* __restrict__ Wt3) {
    __shared__ float tile[64][65];
    int bid = blockIdx.x;
    int mat = bid >> 6, sub = bid & 63;
    const float* W = (mat == 0) ? W0 : (mat == 1) ? W1 : (mat == 2) ? W2 : W3;
    unsigned short* Wt = (mat == 0) ? Wt2 : (mat == 1) ? (Wt2 + 512 * 512)
                       : (mat == 2) ? Wt3 : (Wt3 + 512 * 512);
    int n0 = (sub & 7) * 64, k0 = (sub >> 3) * 64;
    int lr = threadIdx.x >> 4;
    int lc = (threadIdx.x & 15) << 2;
    for (int r = lr; r < 64; r += 16) {
        float4 v = *(const float4*)(W + (size_t)(k0 + r) * 512 + n0 + lc);
        tile[r][lc] = v.x; tile[r][lc + 1] = v.y; tile[r][lc + 2] = v.z; tile[r][lc + 3] = v.w;
    }
    __syncthreads();
    for (int r = lr; r < 64; r += 16) {
        ushort4 o;
        o.x = f2bf(tile[lc + 0][r]); o.y = f2bf(tile[lc + 1][r]);
        o.z = f2bf(tile[lc + 2][r]); o.w = f2bf(tile[lc + 3][r]);
        *(ushort4*)(Wt + (size_t)(n0 + r) * 512 + k0 + lc) = o;
    }
}

// ---------- bf16 MFMA GEMM: global_load_lds + XOR-swizzled LDS, XCD-swizzled grid ----------
#define BM 128
#define BN 128

__global__ __launch_bounds__(256) void k_gemm_bf16(
        const unsigned short* __restrict__ Ab,
        const unsigned short* __restrict__ Bt,
        unsigned short* __restrict__ xl, unsigned short* __restrict__ xr) {
    __shared__ unsigned short As[BM * 64];
    __shared__ unsigned short Bs[BN * 64];
    int t = threadIdx.x;
    int bid = blockIdx.x;
    int xcd = bid & 7, rr_ = bid >> 3;
    int m0 = (xcd * 16 + (rr_ & 15)) * BM;
    int n0 = (rr_ >> 4) * BN;
    int wv = t >> 6, lane = t & 63;
    int wm = (wv >> 1) * 64, wn = (wv & 1) * 64;
    int lrow = lane & 15, quad = lane >> 4;
    int lr = lane >> 3;        // row-in-8 for staging
    int lc = lane & 7;         // LDS chunk position
    int cg = lc ^ lr;          // global chunk to fetch (XOR swizzle; row&7 == lr)
    floatx4 acc[4][4] = {};
    for (int k0 = 0; k0 < 512; k0 += 64) {
        __syncthreads();
#pragma unroll
        for (int it = 0; it < 4; it++) {
            int rb = wv * 4 + it;          // rowBlock 0..15 (8 rows each)
            int row = rb * 8 + lr;
            gl_lds16(Ab + (size_t)(m0 + row) * 512 + k0 + cg * 8, As + rb * 512);
            gl_lds16(Bt + (size_t)(n0 + row) * 512 + k0 + cg * 8, Bs + rb * 512);
        }
        __syncthreads();
#pragma unroll
        for (int ko = 0; ko < 2; ko++) {
            bf16x8 af[4], bfr[4];
            int cp = ((ko * 4 + quad) ^ (lrow & 7)) * 8;
#pragma unroll
            for (int i = 0; i < 4; i++) {
                af[i]  = *(const bf16x8*)&As[(wm + i * 16 + lrow) * 64 + cp];
                bfr[i] = *(const bf16x8*)&Bs[(wn + i * 16 + lrow) * 64 + cp];
            }
#pragma unroll
            for (int i = 0; i < 4; i++)
#pragma unroll
                for (int j = 0; j < 4; j++)
                    acc[i][j] = __builtin_amdgcn_mfma_f32_16x16x32_bf16(af[i], bfr[j], acc[i][j], 0, 0, 0);
        }
    }
#pragma unroll
    for (int i = 0; i < 4; i++) {
        int row = m0 + wm + i * 16 + quad * 4;
#pragma unroll
        for (int j = 0; j < 4; j++) {
            int col = n0 + wn + j * 16 + lrow;
            unsigned short* dstp = (col < 512) ? (xl + (size_t)row * 512 + col)
                                               : (xr + (size_t)row * 512 + (col - 512));
#pragma unroll
            for (int r = 0; r < 4; r++) dstp[(size_t)r * 512] = f2bf(acc[i][j][r]);
        }
    }
}

// ---------- fused GATv2 edge phase: 2-wide edges, no-max softmax ----------
__global__ __launch_bounds__(256) void k_attn(
        const unsigned short* __restrict__ xl, const unsigned short* __restrict__ xr,
        const int* __restrict__ rp, const int* __restrict__ csrc,
        const float2* __restrict__ ce, const float* __restrict__ We,
        const float* __restrict__ att, const float* __restrict__ bias,
        float* __restrict__ out) {
    int n = blockIdx.x * 4 + (threadIdx.x >> 6);
    int lane = threadIdx.x & 63;
    int c0 = lane << 3;
    float wv0[8], wv1[8], av[8], rv[8];
    {
        float4 a = *(const float4*)(We + c0), b = *(const float4*)(We + c0 + 4);
        wv0[0]=a.x; wv0[1]=a.y; wv0[2]=a.z; wv0[3]=a.w; wv0[4]=b.x; wv0[5]=b.y; wv0[6]=b.z; wv0[7]=b.w;
        a = *(const float4*)(We + 512 + c0); b = *(const float4*)(We + 512 + c0 + 4);
        wv1[0]=a.x; wv1[1]=a.y; wv1[2]=a.z; wv1[3]=a.w; wv1[4]=b.x; wv1[5]=b.y; wv1[6]=b.z; wv1[7]=b.w;
        a = *(const float4*)(att + c0); b = *(const float4*)(att + c0 + 4);
        av[0]=a.x; av[1]=a.y; av[2]=a.z; av[3]=a.w; av[4]=b.x; av[5]=b.y; av[6]=b.z; av[7]=b.w;
        uint4 vr = *(const uint4*)(xr + (size_t)n * 512 + c0);
        unpk8(vr, rv);
    }
    float l = 0.f;
    float acc[8] = {0.f, 0.f, 0.f, 0.f, 0.f, 0.f, 0.f, 0.f};
    int beg = rp[n], end = rp[n + 1];
    uint4 cv0 = {}, cv1 = {};
    float2 ce0 = {}, ce1 = {};
    if (beg < end) {
        int i1 = (beg + 1 < end) ? beg + 1 : end - 1;
        cv0 = *(const uint4*)(xl + (size_t)csrc[beg] * 512 + c0);
        ce0 = ce[beg];
        cv1 = *(const uint4*)(xl + (size_t)csrc[i1] * 512 + c0);
        ce1 = ce[i1];
    }
    int i = beg;
    for (; i + 1 < end; i += 2) {
        uint4 a0 = cv0, a1 = cv1;
        float2 d0 = ce0, d1 = ce1;
        int q0 = i + 2, q1 = i + 3;
        q0 = (q0 < end) ? q0 : end - 1;
        q1 = (q1 < end) ? q1 : end - 1;
        cv0 = *(const uint4*)(xl + (size_t)csrc[q0] * 512 + c0);
        ce0 = ce[q0];
        cv1 = *(const uint4*)(xl + (size_t)csrc[q1] * 512 + c0);
        ce1 = ce[q1];
        float lv0[8], lv1[8];
        unpk8(a0, lv0);
        unpk8(a1, lv1);
        float p0 = 0.f, p1 = 0.f;
#pragma unroll
        for (int j = 0; j < 8; j++) {
            float v0 = lv0[j] + rv[j] + d0.x * wv0[j] + d0.y * wv1[j];
            float v1 = lv1[j] + rv[j] + d1.x * wv0[j] + d1.y * wv1[j];
            v0 = fmaxf(v0, 0.2f * v0);   // leaky_relu(0.2)
            v1 = fmaxf(v1, 0.2f * v1);
            p0 += av[j] * v0;
            p1 += av[j] * v1;
        }
        p0 += __shfl_xor(p0, 1);  p1 += __shfl_xor(p1, 1);
        p0 += __shfl_xor(p0, 2);  p1 += __shfl_xor(p1, 2);
        p0 += __shfl_xor(p0, 4);  p1 += __shfl_xor(p1, 4);
        p0 += __shfl_xor(p0, 8);  p1 += __shfl_xor(p1, 8);
        float w0 = __expf(fminf(p0, 60.f));
        float w1 = __expf(fminf(p1, 60.f));
        l += w0 + w1;
#pragma unroll
        for (int j = 0; j < 8; j++)
            acc[j] += w0 * lv0[j] + w1 * lv1[j];
    }
    if (i < end) {
        float lv[8];
        unpk8(cv0, lv);
        float p = 0.f;
#pragma unroll
        for (int j = 0; j < 8; j++) {
            float v = lv[j] + rv[j] + ce0.x * wv0[j] + ce0.y * wv1[j];
            v = fmaxf(v, 0.2f * v);
            p += av[j] * v;
        }
        p += __shfl_xor(p, 1);
        p += __shfl_xor(p, 2);
        p += __shfl_xor(p, 4);
        p += __shfl_xor(p, 8);
        float w = __expf(fminf(p, 60.f));
        l += w;
#pragma unroll
        for (int j = 0; j < 8; j++) acc[j] += w * lv[j];
    }
    float inv = 1.f / (l + 1e-16f);
    const float* bb = bias + c0;
    float4 b0 = *(const float4*)bb, b1 = *(const float4*)(bb + 4);
    float* o = out + (size_t)n * 512 + c0;
    *(float4*)o = make_float4(acc[0] * inv + b0.x, acc[1] * inv + b0.y,
                              acc[2] * inv + b0.z, acc[3] * inv + b0.w);
    *(float4*)(o + 4) = make_float4(acc[4] * inv + b1.x, acc[5] * inv + b1.y,
                                    acc[6] * inv + b1.z, acc[7] * inv + b1.w);
}

// ---------- BN stats + last-block finalize ----------
__global__ __launch_bounds__(256) void k_bnstat(const float* __restrict__ x,
                                                double* __restrict__ sum,
                                                double* __restrict__ sumsq,
                                                int* __restrict__ counter,
                                                const float* __restrict__ g,
                                                float* __restrict__ mean,
                                                float* __restrict__ scale) {
    int t = threadIdx.x;
    int r0 = blockIdx.x * 64;
    float s0 = 0.f, s1 = 0.f, q0 = 0.f, q1 = 0.f;
    for (int r = r0; r < r0 + 64; r++) {
        float v0 = x[(size_t)r * 512 + t];
        float v1 = x[(size_t)r * 512 + t + 256];
        s0 += v0; q0 += v0 * v0;
        s1 += v1; q1 += v1 * v1;
    }
    atomicAdd(sum + t, (double)s0);
    atomicAdd(sum + t + 256, (double)s1);
    atomicAdd(sumsq + t, (double)q0);
    atomicAdd(sumsq + t + 256, (double)q1);
    __threadfence();
    __syncthreads();   // ALL threads' atomics issued+fenced before t0 signals done
    __shared__ int isLast;
    if (t == 0) isLast = (atomicAdd(counter, 1) == 255);
    __syncthreads();
    if (isLast) {
        // atomicExch = coherent read + reset-for-next-layer in one op
        for (int c = t; c < 512; c += 256) {
            double s = __longlong_as_double(atomicExch((unsigned long long*)(sum + c), 0ull));
            double q = __longlong_as_double(atomicExch((unsigned long long*)(sumsq + c), 0ull));
            double mu = s * (1.0 / NN);
            double var = q * (1.0 / NN) - mu * mu;
            mean[c] = (float)mu;
            scale[c] = g[c] * rsqrtf((float)var + 1e-5f);
        }
        if (t == 0) atomicExch(counter, 0);
    }
}

// ---------- BN apply + ELU + optional residual, float4-vectorized ----------
__global__ void k_bnapply(const float* __restrict__ v, const float* __restrict__ resid,
                          const float* __restrict__ mean, const float* __restrict__ scale,
                          const float* __restrict__ beta, float* __restrict__ out,
                          unsigned short* __restrict__ outb) {
    int i = (blockIdx.x * 256 + threadIdx.x) << 2;
    int c = i & 511;
    float4 vv = *(const float4*)(v + i);
    float4 mm = *(const float4*)(mean + c);
    float4 ss = *(const float4*)(scale + c);
    float4 be = *(const float4*)(beta + c);
    float y0 = (vv.x - mm.x) * ss.x + be.x;
    float y1 = (vv.y - mm.y) * ss.y + be.y;
    float y2 = (vv.z - mm.z) * ss.z + be.z;
    float y3 = (vv.w - mm.w) * ss.w + be.w;
    y0 = y0 > 0.f ? y0 : expm1f(y0);
    y1 = y1 > 0.f ? y1 : expm1f(y1);
    y2 = y2 > 0.f ? y2 : expm1f(y2);
    y3 = y3 > 0.f ? y3 : expm1f(y3);
    if (resid) {
        float4 rr = *(const float4*)(resid + i);
        y0 += rr.x; y1 += rr.y; y2 += rr.z; y3 += rr.w;
    }
    *(float4*)(out + i) = make_float4(y0, y1, y2, y3);
    if (outb) {
        ushort4 o;
        o.x = f2bf(y0); o.y = f2bf(y1); o.z = f2bf(y2); o.w = f2bf(y3);
        *(ushort4*)(outb + i) = o;
    }
}

// ---------- pooling ----------
__global__ __launch_bounds__(256) void k_pool(const float* __restrict__ x,
                                              const int* __restrict__ batch,
                                              float* __restrict__ pooled) {
    __shared__ float lacc[NG][512];
    int t = threadIdx.x;
    for (int i = t; i < NG * 512; i += 256) ((float*)lacc)[i] = 0.f;
    __syncthreads();
    int r0 = blockIdx.x * 64;
    for (int r = r0; r < r0 + 64; r++) {
        int g = batch[r];
        lacc[g][t] += x[(size_t)r * 512 + t];
        lacc[g][t + 256] += x[(size_t)r * 512 + t + 256];
    }
    __syncthreads();
    int gmin = batch[r0], gmax = batch[r0 + 63];
    for (int g = gmin; g <= gmax; g++)
        for (int i = t; i < 512; i += 256)
            atomicAdd(&pooled[g * 512 + i], lacc[g][i]);
}

// ---------- MLP head ----------
__global__ __launch_bounds__(256) void k_mlp1(const float* __restrict__ pooled,
                                              const int* __restrict__ gcnt,
                                              const float* __restrict__ W1,
                                              const float* __restrict__ b1,
                                              float* __restrict__ h1) {
    int g = blockIdx.x, o = threadIdx.x;
    float dot = 0.f;
    for (int c = 0; c < 512; c++) dot += pooled[g * 512 + c] * W1[c * 256 + o];
    float s = dot / (float)gcnt[g] + b1[o];
    h1[g * 256 + o] = fmaxf(s, 0.f);
}

// mlp2 + classifier fused: block = one graph
__global__ __launch_bounds__(256) void k_head(const float* __restrict__ h1,
                                              const float* __restrict__ W2,
                                              const float* __restrict__ b2,
                                              const float* __restrict__ clsW,
                                              const float* __restrict__ clsb,
                                              float* __restrict__ outp) {
    __shared__ float es[256];
    int g = blockIdx.x, o = threadIdx.x;
    float s = b2[o];
    for (int c = 0; c < 256; c++) s += h1[g * 256 + c] * W2[c * 256 + o];
    outp[NG * 12 + g * 256 + o] = s;  // emb
    es[o] = s;
    __syncthreads();
    if (o < 12) {
        float lg = clsb[o];
        for (int c = 0; c < 256; c++) lg += es[c] * clsW[c * 12 + o];
        outp[g * 12 + o] = lg;  // logits
    }
}

extern "C" void kernel_launch(void* const* d_in, const int* in_sizes, int n_in,
                              void* d_out, int out_size, void* d_ws, size_t ws_size,
                              hipStream_t stream) {
    const float* x     = (const float*)d_in[0];
    const float* ea    = (const float*)d_in[1];
    const int*   ei    = (const int*)d_in[2];
    const int*   batch = (const int*)d_in[3];
    const int* src = ei;
    const int* dst = ei + NE;

    float* base = (float*)d_ws;
    size_t off = 0;
    auto alloc = [&](size_t n) -> float* {   // n = FLOAT count
        float* p = base + off;
        off += (n + 255) & ~(size_t)255;
        return p;
    };
    unsigned short* xl  = (unsigned short*)alloc((size_t)NN * 256);  // [NN,512] bf16
    unsigned short* xr  = (unsigned short*)alloc((size_t)NN * 256);
    float*    bufA  = alloc((size_t)NN * 512);
    float*    bufB  = alloc((size_t)NN * 512);
    unsigned short* Xb  = (unsigned short*)alloc((size_t)NN * 256);  // [NN,512] bf16
    unsigned short* Wt2 = (unsigned short*)alloc(512 * 1024 / 2);    // [1024,512] bf16
    unsigned short* Wt3 = (unsigned short*)alloc(512 * 1024 / 2);
    int*      cnt   = (int*)alloc(NN);
    int*      rp    = (int*)alloc(NN + 1);
    int*      offp  = (int*)alloc(NN);
    int*      csrc  = (int*)alloc(NE);
    float2*   ce    = (float2*)alloc((size_t)NE * 2);
    double*   bsum  = (double*)alloc(2048);   // 1024 doubles: bsum[512] | bsq[512]
    double*   bsq   = bsum + 512;
    int*      bcnt  = (int*)alloc(64);        // contiguous after bsum block
    float*    bmean = alloc(512);
    float*    bscale= alloc(512);
    float*    pooled= alloc(NG * 512);
    int*      gcnt  = (int*)alloc(NG);
    float*    h1    = alloc(NG * 256);
    float*    outp  = (float*)d_out;  // [0,96): logits, [96,2144): emb

    hipMemsetAsync(cnt, 0, NN * sizeof(int), stream);
    hipMemsetAsync(bsum, 0, 2048 * sizeof(float) + 64 * sizeof(int), stream);  // bsum+bsq+bcnt
    k_hist<<<NE / 256, 256, 0, stream>>>(dst, cnt);
    k_scan<<<1, 1024, 0, stream>>>(cnt, rp, offp, batch, gcnt);
    k_fill<<<NE / 256, 256, 0, stream>>>(dst, src, ea, offp, csrc, ce);
    k_wt4<<<256, 256, 0, stream>>>((const float*)d_in[11], (const float*)d_in[12],
                                   (const float*)d_in[18], (const float*)d_in[19], Wt2, Wt3);

    float* X = bufA;
    float* Y = bufB;
    for (int l = 0; l < 3; l++) {
        const float* Wl  = (const float*)d_in[4 + l * 7 + 0];
        const float* Wr  = (const float*)d_in[4 + l * 7 + 1];
        const float* We  = (const float*)d_in[4 + l * 7 + 2];
        const float* att = (const float*)d_in[4 + l * 7 + 3];
        const float* cb  = (const float*)d_in[4 + l * 7 + 4];
        const float* bg  = (const float*)d_in[4 + l * 7 + 5];
        const float* bb  = (const float*)d_in[4 + l * 7 + 6];

        if (l == 0) {
            k_lin1<<<NN / 4, 256, 0, stream>>>(x, Wl, Wr, xl, xr);
        } else {
            k_gemm_bf16<<<1024, 256, 0, stream>>>(Xb, (l == 1) ? Wt2 : Wt3, xl, xr);
        }
        k_attn<<<NN / 4, 256, 0, stream>>>(xl, xr, rp, csrc, ce, We, att, cb, Y);

        k_bnstat<<<256, 256, 0, stream>>>(Y, bsum, bsq, bcnt, bg, bmean, bscale);
        k_bnapply<<<(size_t)NN * 512 / 1024, 256, 0, stream>>>(
            Y, (l == 0) ? nullptr : X, bmean, bscale, bb, Y,
            (l < 2) ? Xb : nullptr);

        float* tmp = X; X = Y; Y = tmp;
    }

    hipMemsetAsync(pooled, 0, NG * 512 * sizeof(float), stream);
    k_pool<<<NN / 64, 256, 0, stream>>>(X, batch, pooled);

    const float* geW1 = (const float*)d_in[25];
    const float* geb1 = (const float*)d_in[26];
    const float* geW2 = (const float*)d_in[27];
    const float* geb2 = (const float*)d_in[28];
    const float* clsW = (const float*)d_in[29];
    const float* clsb = (const float*)d_in[30];

    k_mlp1<<<NG, 256, 0, stream>>>(pooled, gcnt, geW1, geb1, h1);
    k_head<<<NG, 256, 0, stream>>>(h1, geW2, geb2, clsW, clsb, outp);
}

// Round 12
// 577.640 us; speedup vs baseline: 1.0010x; 1.0010x over previous
//
#include <hip/hip_runtime.h>
#include <math.h>

#define NN    16384
#define NE    262144
#define NHEAD 4
#define HC    512
#define NG    8

typedef __bf16 bf16x8 __attribute__((ext_vector_type(8)));
typedef float floatx4 __attribute__((ext_vector_type(4)));

__device__ __forceinline__ unsigned short f2bf(float f) {
    union { float f; unsigned u; } v{f};
    unsigned r = v.u + 0x7FFFu + ((v.u >> 16) & 1u);  // RNE
    return (unsigned short)(r >> 16);
}

__device__ __forceinline__ void unpk8(uint4 v, float* f) {
    f[0] = __uint_as_float(v.x << 16); f[1] = __uint_as_float(v.x & 0xFFFF0000u);
    f[2] = __uint_as_float(v.y << 16); f[3] = __uint_as_float(v.y & 0xFFFF0000u);
    f[4] = __uint_as_float(v.z << 16); f[5] = __uint_as_float(v.z & 0xFFFF0000u);
    f[6] = __uint_as_float(v.w << 16); f[7] = __uint_as_float(v.w & 0xFFFF0000u);
}

// ---------- CSR build ----------
__global__ void k_hist(const int* __restrict__ dst, int* __restrict__ cnt) {
    int e = blockIdx.x * 256 + threadIdx.x;
    if (e < NE) atomicAdd(&cnt[dst[e]], 1);
}

__global__ __launch_bounds__(1024) void k_scan(const int* __restrict__ cnt,
                                               int* __restrict__ rp,
                                               int* __restrict__ offp,
                                               const int* __restrict__ batch,
                                               int* __restrict__ gcnt) {
    __shared__ int part[1024];
    int t = threadIdx.x;
    // fused k_gcnt: batch sorted -> counts via binary searches (threads 0..7)
    if (t < NG) {
        int lb[2];
#pragma unroll
        for (int q = 0; q < 2; q++) {
            int target = t + q;
            int lo = 0, hi = NN;
            while (lo < hi) {
                int mid = (lo + hi) >> 1;
                if (batch[mid] < target) lo = mid + 1; else hi = mid;
            }
            lb[q] = lo;
        }
        gcnt[t] = lb[1] - lb[0];
    }
    int base = t * 16;
    int loc[16];
    int s = 0;
#pragma unroll
    for (int i = 0; i < 16; i++) { loc[i] = s; s += cnt[base + i]; }
    part[t] = s;
    __syncthreads();
    for (int off = 1; off < 1024; off <<= 1) {
        int v = 0;
        if (t >= off) v = part[t - off];
        __syncthreads();
        if (t >= off) part[t] += v;
        __syncthreads();
    }
    int excl = (t == 0) ? 0 : part[t - 1];
#pragma unroll
    for (int i = 0; i < 16; i++) {
        int r = excl + loc[i];
        rp[base + i] = r;
        offp[base + i] = r;
    }
    if (t == 1023) rp[NN] = excl + s;
}

// scatter src + edge_attr directly into CSR slots
__global__ void k_fill(const int* __restrict__ dst, const int* __restrict__ src,
                       const float* __restrict__ ea, int* __restrict__ offp,
                       int* __restrict__ csrc, float2* __restrict__ ce) {
    int e = blockIdx.x * 256 + threadIdx.x;
    if (e < NE) {
        int d = dst[e];
        int pos = atomicAdd(&offp[d], 1);
        csrc[pos] = src[e];
        ce[pos] = *(const float2*)(ea + 2 * (size_t)e);
    }
}

// ---------- layer-1 linear (K=5), bf16 out, vectorized ----------
__global__ __launch_bounds__(256) void k_lin1(const float* __restrict__ x,
                                              const float* __restrict__ Wl,
                                              const float* __restrict__ Wr,
                                              unsigned short* __restrict__ xl,
                                              unsigned short* __restrict__ xr) {
    int n = blockIdx.x * 4 + (threadIdx.x >> 6);
    int lane = threadIdx.x & 63;
    int j0 = lane << 3;
    float xs[5];
#pragma unroll
    for (int k = 0; k < 5; k++) xs[k] = x[n * 5 + k];
    float al[8] = {}, ar[8] = {};
#pragma unroll
    for (int k = 0; k < 5; k++) {
        float4 wl0 = *(const float4*)(Wl + k * 512 + j0);
        float4 wl1 = *(const float4*)(Wl + k * 512 + j0 + 4);
        float4 wr0 = *(const float4*)(Wr + k * 512 + j0);
        float4 wr1 = *(const float4*)(Wr + k * 512 + j0 + 4);
        al[0] += xs[k] * wl0.x; al[1] += xs[k] * wl0.y; al[2] += xs[k] * wl0.z; al[3] += xs[k] * wl0.w;
        al[4] += xs[k] * wl1.x; al[5] += xs[k] * wl1.y; al[6] += xs[k] * wl1.z; al[7] += xs[k] * wl1.w;
        ar[0] += xs[k] * wr0.x; ar[1] += xs[k] * wr0.y; ar[2] += xs[k] * wr0.z; ar[3] += xs[k] * wr0.w;
        ar[4] += xs[k] * wr1.x; ar[5] += xs[k] * wr1.y; ar[6] += xs[k] * wr1.z; ar[7] += xs[k] * wr1.w;
    }
    ushort4 o0, o1;
    o0.x = f2bf(al[0]); o0.y = f2bf(al[1]); o0.z = f2bf(al[2]); o0.w = f2bf(al[3]);
    o1.x = f2bf(al[4]); o1.y = f2bf(al[5]); o1.z = f2bf(al[6]); o1.w = f2bf(al[7]);
    *(ushort4*)(xl + (size_t)n * 512 + j0) = o0;
    *(ushort4*)(xl + (size_t)n * 512 + j0 + 4) = o1;
    o0.x = f2bf(ar[0]); o0.y = f2bf(ar[1]); o0.z = f2bf(ar[2]); o0.w = f2bf(ar[3]);
    o1.x = f2bf(ar[4]); o1.y = f2bf(ar[5]); o1.z = f2bf(ar[6]); o1.w = f2bf(ar[7]);
    *(ushort4*)(xr + (size_t)n * 512 + j0) = o0;
    *(ushort4*)(xr + (size_t)n * 512 + j0 + 4) = o1;
}

// ---------- 4 weight transposes in one dispatch ----------
__global__ __launch_bounds__(256) void k_wt4(const float* __restrict__ W0,
                                             const float* __restrict__ W1,
                                             const float* __restrict__ W2,
                                             const float* __restrict__ W3,
                                             unsigned short* __restrict__ Wt2,
                                             unsigned short* __restrict__ Wt3) {
    __shared__ float tile[64][65];
    int bid = blockIdx.x;
    int mat = bid >> 6, sub = bid & 63;
    const float* W = (mat == 0) ? W0 : (mat == 1) ? W1 : (mat == 2) ? W2 : W3;
    unsigned short* Wt = (mat == 0) ? Wt2 : (mat == 1) ? (Wt2 + 512 * 512)
                       : (mat == 2) ? Wt3 : (Wt3 + 512 * 512);
    int n0 = (sub & 7) * 64, k0 = (sub >> 3) * 64;
    int lr = threadIdx.x >> 4;
    int lc = (threadIdx.x & 15) << 2;
    for (int r = lr; r < 64; r += 16) {
        float4 v = *(const float4*)(W + (size_t)(k0 + r) * 512 + n0 + lc);
        tile[r][lc] = v.x; tile[r][lc + 1] = v.y; tile[r][lc + 2] = v.z; tile[r][lc + 3] = v.w;
    }
    __syncthreads();
    for (int r = lr; r < 64; r += 16) {
        ushort4 o;
        o.x = f2bf(tile[lc + 0][r]); o.y = f2bf(tile[lc + 1][r]);
        o.z = f2bf(tile[lc + 2][r]); o.w = f2bf(tile[lc + 3][r]);
        *(ushort4*)(Wt + (size_t)(n0 + r) * 512 + k0 + lc) = o;
    }
}

// ---------- bf16 MFMA GEMM: round-8 proven config (LDK=72 padded, VGPR staging) ----------
#define BM 128
#define BN 128
#define BK 64
#define LDK 72  // 144B row stride rotates bank origin per row -> conflict-free b128 reads

__global__ __launch_bounds__(256) void k_gemm_bf16(
        const unsigned short* __restrict__ Ab,
        const unsigned short* __restrict__ Bt,
        unsigned short* __restrict__ xl, unsigned short* __restrict__ xr) {
    __shared__ unsigned short As[BM * LDK];
    __shared__ unsigned short Bs[BN * LDK];
    int t = threadIdx.x;
    int bid = blockIdx.x;
    int xcd = bid & 7, r = bid >> 3;
    int m0 = (xcd * 16 + (r & 15)) * BM;
    int n0 = (r >> 4) * BN;
    int wid = t >> 6, lane = t & 63;
    int wm = (wid >> 1) * 64, wn = (wid & 1) * 64;
    int lrow = lane & 15, quad = lane >> 4;
    floatx4 acc[4][4] = {};
    for (int k0 = 0; k0 < 512; k0 += BK) {
        __syncthreads();
#pragma unroll
        for (int it = 0; it < 4; it++) {
            int cid = it * 256 + t;
            int row = cid >> 3, ch = cid & 7;
            uint4 va = *(const uint4*)(Ab + (size_t)(m0 + row) * 512 + k0 + ch * 8);
            *(uint4*)&As[row * LDK + ch * 8] = va;
            uint4 vb = *(const uint4*)(Bt + (size_t)(n0 + row) * 512 + k0 + ch * 8);
            *(uint4*)&Bs[row * LDK + ch * 8] = vb;
        }
        __syncthreads();
#pragma unroll
        for (int ko = 0; ko < 2; ko++) {
            bf16x8 af[4], bfr[4];
#pragma unroll
            for (int i = 0; i < 4; i++) {
                af[i]  = *(const bf16x8*)&As[(wm + i * 16 + lrow) * LDK + ko * 32 + quad * 8];
                bfr[i] = *(const bf16x8*)&Bs[(wn + i * 16 + lrow) * LDK + ko * 32 + quad * 8];
            }
#pragma unroll
            for (int i = 0; i < 4; i++)
#pragma unroll
                for (int j = 0; j < 4; j++)
                    acc[i][j] = __builtin_amdgcn_mfma_f32_16x16x32_bf16(af[i], bfr[j], acc[i][j], 0, 0, 0);
        }
    }
#pragma unroll
    for (int i = 0; i < 4; i++) {
        int row = m0 + wm + i * 16 + quad * 4;
#pragma unroll
        for (int j = 0; j < 4; j++) {
            int col = n0 + wn + j * 16 + lrow;
            unsigned short* dstp = (col < 512) ? (xl + (size_t)row * 512 + col)
                                               : (xr + (size_t)row * 512 + (col - 512));
#pragma unroll
            for (int rr = 0; rr < 4; rr++) dstp[(size_t)rr * 512] = f2bf(acc[i][j][rr]);
        }
    }
}

// ---------- fused GATv2 edge phase: 2-wide edges, no-max softmax ----------
__global__ __launch_bounds__(256) void k_attn(
        const unsigned short* __restrict__ xl, const unsigned short* __restrict__ xr,
        const int* __restrict__ rp, const int* __restrict__ csrc,
        const float2* __restrict__ ce, const float* __restrict__ We,
        const float* __restrict__ att, const float* __restrict__ bias,
        float* __restrict__ out) {
    int n = blockIdx.x * 4 + (threadIdx.x >> 6);
    int lane = threadIdx.x & 63;
    int c0 = lane << 3;
    float wv0[8], wv1[8], av[8], rv[8];
    {
        float4 a = *(const float4*)(We + c0), b = *(const float4*)(We + c0 + 4);
        wv0[0]=a.x; wv0[1]=a.y; wv0[2]=a.z; wv0[3]=a.w; wv0[4]=b.x; wv0[5]=b.y; wv0[6]=b.z; wv0[7]=b.w;
        a = *(const float4*)(We + 512 + c0); b = *(const float4*)(We + 512 + c0 + 4);
        wv1[0]=a.x; wv1[1]=a.y; wv1[2]=a.z; wv1[3]=a.w; wv1[4]=b.x; wv1[5]=b.y; wv1[6]=b.z; wv1[7]=b.w;
        a = *(const float4*)(att + c0); b = *(const float4*)(att + c0 + 4);
        av[0]=a.x; av[1]=a.y; av[2]=a.z; av[3]=a.w; av[4]=b.x; av[5]=b.y; av[6]=b.z; av[7]=b.w;
        uint4 vr = *(const uint4*)(xr + (size_t)n * 512 + c0);
        unpk8(vr, rv);
    }
    float l = 0.f;
    float acc[8] = {0.f, 0.f, 0.f, 0.f, 0.f, 0.f, 0.f, 0.f};
    int beg = rp[n], end = rp[n + 1];
    uint4 cv0 = {}, cv1 = {};
    float2 ce0 = {}, ce1 = {};
    if (beg < end) {
        int i1 = (beg + 1 < end) ? beg + 1 : end - 1;
        cv0 = *(const uint4*)(xl + (size_t)csrc[beg] * 512 + c0);
        ce0 = ce[beg];
        cv1 = *(const uint4*)(xl + (size_t)csrc[i1] * 512 + c0);
        ce1 = ce[i1];
    }
    int i = beg;
    for (; i + 1 < end; i += 2) {
        uint4 a0 = cv0, a1 = cv1;
        float2 d0 = ce0, d1 = ce1;
        int q0 = i + 2, q1 = i + 3;
        q0 = (q0 < end) ? q0 : end - 1;
        q1 = (q1 < end) ? q1 : end - 1;
        cv0 = *(const uint4*)(xl + (size_t)csrc[q0] * 512 + c0);
        ce0 = ce[q0];
        cv1 = *(const uint4*)(xl + (size_t)csrc[q1] * 512 + c0);
        ce1 = ce[q1];
        float lv0[8], lv1[8];
        unpk8(a0, lv0);
        unpk8(a1, lv1);
        float p0 = 0.f, p1 = 0.f;
#pragma unroll
        for (int j = 0; j < 8; j++) {
            float v0 = lv0[j] + rv[j] + d0.x * wv0[j] + d0.y * wv1[j];
            float v1 = lv1[j] + rv[j] + d1.x * wv0[j] + d1.y * wv1[j];
            v0 = fmaxf(v0, 0.2f * v0);   // leaky_relu(0.2)
            v1 = fmaxf(v1, 0.2f * v1);
            p0 += av[j] * v0;
            p1 += av[j] * v1;
        }
        p0 += __shfl_xor(p0, 1);  p1 += __shfl_xor(p1, 1);
        p0 += __shfl_xor(p0, 2);  p1 += __shfl_xor(p1, 2);
        p0 += __shfl_xor(p0, 4);  p1 += __shfl_xor(p1, 4);
        p0 += __shfl_xor(p0, 8);  p1 += __shfl_xor(p1, 8);
        float w0 = __expf(fminf(p0, 60.f));
        float w1 = __expf(fminf(p1, 60.f));
        l += w0 + w1;
#pragma unroll
        for (int j = 0; j < 8; j++)
            acc[j] += w0 * lv0[j] + w1 * lv1[j];
    }
    if (i < end) {
        float lv[8];
        unpk8(cv0, lv);
        float p = 0.f;
#pragma unroll
        for (int j = 0; j < 8; j++) {
            float v = lv[j] + rv[j] + ce0.x * wv0[j] + ce0.y * wv1[j];
            v = fmaxf(v, 0.2f * v);
            p += av[j] * v;
        }
        p += __shfl_xor(p, 1);
        p += __shfl_xor(p, 2);
        p += __shfl_xor(p, 4);
        p += __shfl_xor(p, 8);
        float w = __expf(fminf(p, 60.f));
        l += w;
#pragma unroll
        for (int j = 0; j < 8; j++) acc[j] += w * lv[j];
    }
    float inv = 1.f / (l + 1e-16f);
    const float* bb = bias + c0;
    float4 b0 = *(const float4*)bb, b1 = *(const float4*)(bb + 4);
    float* o = out + (size_t)n * 512 + c0;
    *(float4*)o = make_float4(acc[0] * inv + b0.x, acc[1] * inv + b0.y,
                              acc[2] * inv + b0.z, acc[3] * inv + b0.w);
    *(float4*)(o + 4) = make_float4(acc[4] * inv + b1.x, acc[5] * inv + b1.y,
                                    acc[6] * inv + b1.z, acc[7] * inv + b1.w);
}

// ---------- BN stats + last-block finalize ----------
__global__ __launch_bounds__(256) void k_bnstat(const float* __restrict__ x,
                                                double* __restrict__ sum,
                                                double* __restrict__ sumsq,
                                                int* __restrict__ counter,
                                                const float* __restrict__ g,
                                                float* __restrict__ mean,
                                                float* __restrict__ scale) {
    int t = threadIdx.x;
    int r0 = blockIdx.x * 64;
    float s0 = 0.f, s1 = 0.f, q0 = 0.f, q1 = 0.f;
    for (int r = r0; r < r0 + 64; r++) {
        float v0 = x[(size_t)r * 512 + t];
        float v1 = x[(size_t)r * 512 + t + 256];
        s0 += v0; q0 += v0 * v0;
        s1 += v1; q1 += v1 * v1;
    }
    atomicAdd(sum + t, (double)s0);
    atomicAdd(sum + t + 256, (double)s1);
    atomicAdd(sumsq + t, (double)q0);
    atomicAdd(sumsq + t + 256, (double)q1);
    __threadfence();
    __syncthreads();   // ALL threads' atomics issued+fenced before t0 signals done
    __shared__ int isLast;
    if (t == 0) isLast = (atomicAdd(counter, 1) == 255);
    __syncthreads();
    if (isLast) {
        for (int c = t; c < 512; c += 256) {
            double s = __longlong_as_double(atomicExch((unsigned long long*)(sum + c), 0ull));
            double q = __longlong_as_double(atomicExch((unsigned long long*)(sumsq + c), 0ull));
            double mu = s * (1.0 / NN);
            double var = q * (1.0 / NN) - mu * mu;
            mean[c] = (float)mu;
            scale[c] = g[c] * rsqrtf((float)var + 1e-5f);
        }
        if (t == 0) atomicExch(counter, 0);
    }
}

// ---------- BN apply + ELU + optional residual, float4-vectorized ----------
__global__ void k_bnapply(const float* __restrict__ v, const float* __restrict__ resid,
                          const float* __restrict__ mean, const float* __restrict__ scale,
                          const float* __restrict__ beta, float* __restrict__ out,
                          unsigned short* __restrict__ outb) {
    int i = (blockIdx.x * 256 + threadIdx.x) << 2;
    int c = i & 511;
    float4 vv = *(const float4*)(v + i);
    float4 mm = *(const float4*)(mean + c);
    float4 ss = *(const float4*)(scale + c);
    float4 be = *(const float4*)(beta + c);
    float y0 = (vv.x - mm.x) * ss.x + be.x;
    float y1 = (vv.y - mm.y) * ss.y + be.y;
    float y2 = (vv.z - mm.z) * ss.z + be.z;
    float y3 = (vv.w - mm.w) * ss.w + be.w;
    y0 = y0 > 0.f ? y0 : expm1f(y0);
    y1 = y1 > 0.f ? y1 : expm1f(y1);
    y2 = y2 > 0.f ? y2 : expm1f(y2);
    y3 = y3 > 0.f ? y3 : expm1f(y3);
    if (resid) {
        float4 rr = *(const float4*)(resid + i);
        y0 += rr.x; y1 += rr.y; y2 += rr.z; y3 += rr.w;
    }
    *(float4*)(out + i) = make_float4(y0, y1, y2, y3);
    if (outb) {
        ushort4 o;
        o.x = f2bf(y0); o.y = f2bf(y1); o.z = f2bf(y2); o.w = f2bf(y3);
        *(ushort4*)(outb + i) = o;
    }
}

// ---------- pooling ----------
__global__ __launch_bounds__(256) void k_pool(const float* __restrict__ x,
                                              const int* __restrict__ batch,
                                              float* __restrict__ pooled) {
    __shared__ float lacc[NG][512];
    int t = threadIdx.x;
    for (int i = t; i < NG * 512; i += 256) ((float*)lacc)[i] = 0.f;
    __syncthreads();
    int r0 = blockIdx.x * 64;
    for (int r = r0; r < r0 + 64; r++) {
        int g = batch[r];
        lacc[g][t] += x[(size_t)r * 512 + t];
        lacc[g][t + 256] += x[(size_t)r * 512 + t + 256];
    }
    __syncthreads();
    int gmin = batch[r0], gmax = batch[r0 + 63];
    for (int g = gmin; g <= gmax; g++)
        for (int i = t; i < 512; i += 256)
            atomicAdd(&pooled[g * 512 + i], lacc[g][i]);
}

// ---------- MLP head ----------
__global__ __launch_bounds__(256) void k_mlp1(const float* __restrict__ pooled,
                                              const int* __restrict__ gcnt,
                                              const float* __restrict__ W1,
                                              const float* __restrict__ b1,
                                              float* __restrict__ h1) {
    int g = blockIdx.x, o = threadIdx.x;
    float dot = 0.f;
    for (int c = 0; c < 512; c++) dot += pooled[g * 512 + c] * W1[c * 256 + o];
    float s = dot / (float)gcnt[g] + b1[o];
    h1[g * 256 + o] = fmaxf(s, 0.f);
}

// mlp2 + classifier fused: block = one graph
__global__ __launch_bounds__(256) void k_head(const float* __restrict__ h1,
                                              const float* __restrict__ W2,
                                              const float* __restrict__ b2,
                                              const float* __restrict__ clsW,
                                              const float* __restrict__ clsb,
                                              float* __restrict__ outp) {
    __shared__ float es[256];
    int g = blockIdx.x, o = threadIdx.x;
    float s = b2[o];
    for (int c = 0; c < 256; c++) s += h1[g * 256 + c] * W2[c * 256 + o];
    outp[NG * 12 + g * 256 + o] = s;  // emb
    es[o] = s;
    __syncthreads();
    if (o < 12) {
        float lg = clsb[o];
        for (int c = 0; c < 256; c++) lg += es[c] * clsW[c * 12 + o];
        outp[g * 12 + o] = lg;  // logits
    }
}

extern "C" void kernel_launch(void* const* d_in, const int* in_sizes, int n_in,
                              void* d_out, int out_size, void* d_ws, size_t ws_size,
                              hipStream_t stream) {
    const float* x     = (const float*)d_in[0];
    const float* ea    = (const float*)d_in[1];
    const int*   ei    = (const int*)d_in[2];
    const int*   batch = (const int*)d_in[3];
    const int* src = ei;
    const int* dst = ei + NE;

    float* base = (float*)d_ws;
    size_t off = 0;
    auto alloc = [&](size_t n) -> float* {   // n = FLOAT count
        float* p = base + off;
        off += (n + 255) & ~(size_t)255;
        return p;
    };
    unsigned short* xl  = (unsigned short*)alloc((size_t)NN * 256);  // [NN,512] bf16
    unsigned short* xr  = (unsigned short*)alloc((size_t)NN * 256);
    float*    bufA  = alloc((size_t)NN * 512);
    float*    bufB  = alloc((size_t)NN * 512);
    unsigned short* Xb  = (unsigned short*)alloc((size_t)NN * 256);  // [NN,512] bf16
    unsigned short* Wt2 = (unsigned short*)alloc(512 * 1024 / 2);    // [1024,512] bf16
    unsigned short* Wt3 = (unsigned short*)alloc(512 * 1024 / 2);
    int*      cnt   = (int*)alloc(NN);
    int*      rp    = (int*)alloc(NN + 1);
    int*      offp  = (int*)alloc(NN);
    int*      csrc  = (int*)alloc(NE);
    float2*   ce    = (float2*)alloc((size_t)NE * 2);
    double*   bsum  = (double*)alloc(2048);   // 1024 doubles: bsum[512] | bsq[512]
    double*   bsq   = bsum + 512;
    int*      bcnt  = (int*)alloc(64);        // contiguous after bsum block
    float*    bmean = alloc(512);
    float*    bscale= alloc(512);
    float*    pooled= alloc(NG * 512);
    int*      gcnt  = (int*)alloc(NG);
    float*    h1    = alloc(NG * 256);
    float*    outp  = (float*)d_out;  // [0,96): logits, [96,2144): emb

    hipMemsetAsync(cnt, 0, NN * sizeof(int), stream);
    hipMemsetAsync(bsum, 0, 2048 * sizeof(float) + 64 * sizeof(int), stream);  // bsum+bsq+bcnt
    k_hist<<<NE / 256, 256, 0, stream>>>(dst, cnt);
    k_scan<<<1, 1024, 0, stream>>>(cnt, rp, offp, batch, gcnt);
    k_fill<<<NE / 256, 256, 0, stream>>>(dst, src, ea, offp, csrc, ce);
    k_wt4<<<256, 256, 0, stream>>>((const float*)d_in[11], (const float*)d_in[12],
                                   (const float*)d_in[18], (const float*)d_in[19], Wt2, Wt3);

    float* X = bufA;
    float* Y = bufB;
    for (int l = 0; l < 3; l++) {
        const float* Wl  = (const float*)d_in[4 + l * 7 + 0];
        const float* Wr  = (const float*)d_in[4 + l * 7 + 1];
        const float* We  = (const float*)d_in[4 + l * 7 + 2];
        const float* att = (const float*)d_in[4 + l * 7 + 3];
        const float* cb  = (const float*)d_in[4 + l * 7 + 4];
        const float* bg  = (const float*)d_in[4 + l * 7 + 5];
        const float* bb  = (const float*)d_in[4 + l * 7 + 6];

        if (l == 0) {
            k_lin1<<<NN / 4, 256, 0, stream>>>(x, Wl, Wr, xl, xr);
        } else {
            k_gemm_bf16<<<1024, 256, 0, stream>>>(Xb, (l == 1) ? Wt2 : Wt3, xl, xr);
        }
        k_attn<<<NN / 4, 256, 0, stream>>>(xl, xr, rp, csrc, ce, We, att, cb, Y);

        k_bnstat<<<256, 256, 0, stream>>>(Y, bsum, bsq, bcnt, bg, bmean, bscale);
        k_bnapply<<<(size_t)NN * 512 / 1024, 256, 0, stream>>>(
            Y, (l == 0) ? nullptr : X, bmean, bscale, bb, Y,
            (l < 2) ? Xb : nullptr);

        float* tmp = X; X = Y; Y = tmp;
    }

    hipMemsetAsync(pooled, 0, NG * 512 * sizeof(float), stream);
    k_pool<<<NN / 64, 256, 0, stream>>>(X, batch, pooled);

    const float* geW1 = (const float*)d_in[25];
    const float* geb1 = (const float*)d_in[26];
    const float* geW2 = (const float*)d_in[27];
    const float* geb2 = (const float*)d_in[28];
    const float* clsW = (const float*)d_in[29];
    const float* clsb = (const float*)d_in[30];

    k_mlp1<<<NG, 256, 0, stream>>>(pooled, gcnt, geW1, geb1, h1);
    k_head<<<NG, 256, 0, stream>>>(h1, geW2, geb2, clsW, clsb, outp);
}

// Round 13
// 524.134 us; speedup vs baseline: 1.1032x; 1.1021x over previous
//
#include <hip/hip_runtime.h>
#include <math.h>

#define NN    16384
#define NE    262144
#define NHEAD 4
#define HC    512
#define NG    8

typedef __bf16 bf16x8 __attribute__((ext_vector_type(8)));
typedef float floatx4 __attribute__((ext_vector_type(4)));

__device__ __forceinline__ unsigned short f2bf(float f) {
    union { float f; unsigned u; } v{f};
    unsigned r = v.u + 0x7FFFu + ((v.u >> 16) & 1u);  // RNE
    return (unsigned short)(r >> 16);
}

__device__ __forceinline__ void unpk8(uint4 v, float* f) {
    f[0] = __uint_as_float(v.x << 16); f[1] = __uint_as_float(v.x & 0xFFFF0000u);
    f[2] = __uint_as_float(v.y << 16); f[3] = __uint_as_float(v.y & 0xFFFF0000u);
    f[4] = __uint_as_float(v.z << 16); f[5] = __uint_as_float(v.z & 0xFFFF0000u);
    f[6] = __uint_as_float(v.w << 16); f[7] = __uint_as_float(v.w & 0xFFFF0000u);
}

// ---------- CSR build ----------
__global__ void k_hist(const int* __restrict__ dst, int* __restrict__ cnt) {
    int e = blockIdx.x * 256 + threadIdx.x;
    if (e < NE) atomicAdd(&cnt[dst[e]], 1);
}

__global__ __launch_bounds__(1024) void k_scan(const int* __restrict__ cnt,
                                               int* __restrict__ rp,
                                               int* __restrict__ offp,
                                               const int* __restrict__ batch,
                                               int* __restrict__ gcnt) {
    __shared__ int part[1024];
    int t = threadIdx.x;
    // fused k_gcnt: batch sorted -> counts via binary searches (threads 0..7)
    if (t < NG) {
        int lb[2];
#pragma unroll
        for (int q = 0; q < 2; q++) {
            int target = t + q;
            int lo = 0, hi = NN;
            while (lo < hi) {
                int mid = (lo + hi) >> 1;
                if (batch[mid] < target) lo = mid + 1; else hi = mid;
            }
            lb[q] = lo;
        }
        gcnt[t] = lb[1] - lb[0];
    }
    int base = t * 16;
    int loc[16];
    int s = 0;
#pragma unroll
    for (int i = 0; i < 16; i++) { loc[i] = s; s += cnt[base + i]; }
    part[t] = s;
    __syncthreads();
    for (int off = 1; off < 1024; off <<= 1) {
        int v = 0;
        if (t >= off) v = part[t - off];
        __syncthreads();
        if (t >= off) part[t] += v;
        __syncthreads();
    }
    int excl = (t == 0) ? 0 : part[t - 1];
#pragma unroll
    for (int i = 0; i < 16; i++) {
        int r = excl + loc[i];
        rp[base + i] = r;
        offp[base + i] = r;
    }
    if (t == 1023) rp[NN] = excl + s;
}

// scatter src + edge_attr directly into CSR slots
__global__ void k_fill(const int* __restrict__ dst, const int* __restrict__ src,
                       const float* __restrict__ ea, int* __restrict__ offp,
                       int* __restrict__ csrc, float2* __restrict__ ce) {
    int e = blockIdx.x * 256 + threadIdx.x;
    if (e < NE) {
        int d = dst[e];
        int pos = atomicAdd(&offp[d], 1);
        csrc[pos] = src[e];
        ce[pos] = *(const float2*)(ea + 2 * (size_t)e);
    }
}

// ---------- layer-1 linear (K=5), bf16 out, vectorized ----------
__global__ __launch_bounds__(256) void k_lin1(const float* __restrict__ x,
                                              const float* __restrict__ Wl,
                                              const float* __restrict__ Wr,
                                              unsigned short* __restrict__ xl,
                                              unsigned short* __restrict__ xr) {
    int n = blockIdx.x * 4 + (threadIdx.x >> 6);
    int lane = threadIdx.x & 63;
    int j0 = lane << 3;
    float xs[5];
#pragma unroll
    for (int k = 0; k < 5; k++) xs[k] = x[n * 5 + k];
    float al[8] = {}, ar[8] = {};
#pragma unroll
    for (int k = 0; k < 5; k++) {
        float4 wl0 = *(const float4*)(Wl + k * 512 + j0);
        float4 wl1 = *(const float4*)(Wl + k * 512 + j0 + 4);
        float4 wr0 = *(const float4*)(Wr + k * 512 + j0);
        float4 wr1 = *(const float4*)(Wr + k * 512 + j0 + 4);
        al[0] += xs[k] * wl0.x; al[1] += xs[k] * wl0.y; al[2] += xs[k] * wl0.z; al[3] += xs[k] * wl0.w;
        al[4] += xs[k] * wl1.x; al[5] += xs[k] * wl1.y; al[6] += xs[k] * wl1.z; al[7] += xs[k] * wl1.w;
        ar[0] += xs[k] * wr0.x; ar[1] += xs[k] * wr0.y; ar[2] += xs[k] * wr0.z; ar[3] += xs[k] * wr0.w;
        ar[4] += xs[k] * wr1.x; ar[5] += xs[k] * wr1.y; ar[6] += xs[k] * wr1.z; ar[7] += xs[k] * wr1.w;
    }
    ushort4 o0, o1;
    o0.x = f2bf(al[0]); o0.y = f2bf(al[1]); o0.z = f2bf(al[2]); o0.w = f2bf(al[3]);
    o1.x = f2bf(al[4]); o1.y = f2bf(al[5]); o1.z = f2bf(al[6]); o1.w = f2bf(al[7]);
    *(ushort4*)(xl + (size_t)n * 512 + j0) = o0;
    *(ushort4*)(xl + (size_t)n * 512 + j0 + 4) = o1;
    o0.x = f2bf(ar[0]); o0.y = f2bf(ar[1]); o0.z = f2bf(ar[2]); o0.w = f2bf(ar[3]);
    o1.x = f2bf(ar[4]); o1.y = f2bf(ar[5]); o1.z = f2bf(ar[6]); o1.w = f2bf(ar[7]);
    *(ushort4*)(xr + (size_t)n * 512 + j0) = o0;
    *(ushort4*)(xr + (size_t)n * 512 + j0 + 4) = o1;
}

// ---------- 4 weight transposes in one dispatch ----------
__global__ __launch_bounds__(256) void k_wt4(const float* __restrict__ W0,
                                             const float* __restrict__ W1,
                                             const float* __restrict__ W2,
                                             const float* __restrict__ W3,
                                             unsigned short* __restrict__ Wt2,
                                             unsigned short* __restrict__ Wt3) {
    __shared__ float tile[64][65];
    int bid = blockIdx.x;
    int mat = bid >> 6, sub = bid & 63;
    const float* W = (mat == 0) ? W0 : (mat == 1) ? W1 : (mat == 2) ? W2 : W3;
    unsigned short* Wt = (mat == 0) ? Wt2 : (mat == 1) ? (Wt2 + 512 * 512)
                       : (mat == 2) ? Wt3 : (Wt3 + 512 * 512);
    int n0 = (sub & 7) * 64, k0 = (sub >> 3) * 64;
    int lr = threadIdx.x >> 4;
    int lc = (threadIdx.x & 15) << 2;
    for (int r = lr; r < 64; r += 16) {
        float4 v = *(const float4*)(W + (size_t)(k0 + r) * 512 + n0 + lc);
        tile[r][lc] = v.x; tile[r][lc + 1] = v.y; tile[r][lc + 2] = v.z; tile[r][lc + 3] = v.w;
    }
    __syncthreads();
    for (int r = lr; r < 64; r += 16) {
        ushort4 o;
        o.x = f2bf(tile[lc + 0][r]); o.y = f2bf(tile[lc + 1][r]);
        o.z = f2bf(tile[lc + 2][r]); o.w = f2bf(tile[lc + 3][r]);
        *(ushort4*)(Wt + (size_t)(n0 + r) * 512 + k0 + lc) = o;
    }
}

// ---------- bf16 MFMA GEMM (LDK=72 padded, VGPR staging, XCD-swizzled grid) ----------
#define BM 128
#define BN 128
#define BK 64
#define LDK 72  // 144B row stride rotates bank origin per row -> conflict-free b128 reads

__global__ __launch_bounds__(256) void k_gemm_bf16(
        const unsigned short* __restrict__ Ab,
        const unsigned short* __restrict__ Bt,
        unsigned short* __restrict__ xl, unsigned short* __restrict__ xr) {
    __shared__ unsigned short As[BM * LDK];
    __shared__ unsigned short Bs[BN * LDK];
    int t = threadIdx.x;
    int bid = blockIdx.x;
    int xcd = bid & 7, r = bid >> 3;
    int m0 = (xcd * 16 + (r & 15)) * BM;
    int n0 = (r >> 4) * BN;
    int wid = t >> 6, lane = t & 63;
    int wm = (wid >> 1) * 64, wn = (wid & 1) * 64;
    int lrow = lane & 15, quad = lane >> 4;
    floatx4 acc[4][4] = {};
    for (int k0 = 0; k0 < 512; k0 += BK) {
        __syncthreads();
#pragma unroll
        for (int it = 0; it < 4; it++) {
            int cid = it * 256 + t;
            int row = cid >> 3, ch = cid & 7;
            uint4 va = *(const uint4*)(Ab + (size_t)(m0 + row) * 512 + k0 + ch * 8);
            *(uint4*)&As[row * LDK + ch * 8] = va;
            uint4 vb = *(const uint4*)(Bt + (size_t)(n0 + row) * 512 + k0 + ch * 8);
            *(uint4*)&Bs[row * LDK + ch * 8] = vb;
        }
        __syncthreads();
#pragma unroll
        for (int ko = 0; ko < 2; ko++) {
            bf16x8 af[4], bfr[4];
#pragma unroll
            for (int i = 0; i < 4; i++) {
                af[i]  = *(const bf16x8*)&As[(wm + i * 16 + lrow) * LDK + ko * 32 + quad * 8];
                bfr[i] = *(const bf16x8*)&Bs[(wn + i * 16 + lrow) * LDK + ko * 32 + quad * 8];
            }
#pragma unroll
            for (int i = 0; i < 4; i++)
#pragma unroll
                for (int j = 0; j < 4; j++)
                    acc[i][j] = __builtin_amdgcn_mfma_f32_16x16x32_bf16(af[i], bfr[j], acc[i][j], 0, 0, 0);
        }
    }
#pragma unroll
    for (int i = 0; i < 4; i++) {
        int row = m0 + wm + i * 16 + quad * 4;
#pragma unroll
        for (int j = 0; j < 4; j++) {
            int col = n0 + wn + j * 16 + lrow;
            unsigned short* dstp = (col < 512) ? (xl + (size_t)row * 512 + col)
                                               : (xr + (size_t)row * 512 + (col - 512));
#pragma unroll
            for (int rr = 0; rr < 4; rr++) dstp[(size_t)rr * 512] = f2bf(acc[i][j][rr]);
        }
    }
}

// ---------- fused GATv2 edge phase: 2-wide edges, no-max softmax ----------
__global__ __launch_bounds__(256) void k_attn(
        const unsigned short* __restrict__ xl, const unsigned short* __restrict__ xr,
        const int* __restrict__ rp, const int* __restrict__ csrc,
        const float2* __restrict__ ce, const float* __restrict__ We,
        const float* __restrict__ att, const float* __restrict__ bias,
        float* __restrict__ out) {
    int n = blockIdx.x * 4 + (threadIdx.x >> 6);
    int lane = threadIdx.x & 63;
    int c0 = lane << 3;
    float wv0[8], wv1[8], av[8], rv[8];
    {
        float4 a = *(const float4*)(We + c0), b = *(const float4*)(We + c0 + 4);
        wv0[0]=a.x; wv0[1]=a.y; wv0[2]=a.z; wv0[3]=a.w; wv0[4]=b.x; wv0[5]=b.y; wv0[6]=b.z; wv0[7]=b.w;
        a = *(const float4*)(We + 512 + c0); b = *(const float4*)(We + 512 + c0 + 4);
        wv1[0]=a.x; wv1[1]=a.y; wv1[2]=a.z; wv1[3]=a.w; wv1[4]=b.x; wv1[5]=b.y; wv1[6]=b.z; wv1[7]=b.w;
        a = *(const float4*)(att + c0); b = *(const float4*)(att + c0 + 4);
        av[0]=a.x; av[1]=a.y; av[2]=a.z; av[3]=a.w; av[4]=b.x; av[5]=b.y; av[6]=b.z; av[7]=b.w;
        uint4 vr = *(const uint4*)(xr + (size_t)n * 512 + c0);
        unpk8(vr, rv);
    }
    float l = 0.f;
    float acc[8] = {0.f, 0.f, 0.f, 0.f, 0.f, 0.f, 0.f, 0.f};
    int beg = rp[n], end = rp[n + 1];
    uint4 cv0 = {}, cv1 = {};
    float2 ce0 = {}, ce1 = {};
    if (beg < end) {
        int i1 = (beg + 1 < end) ? beg + 1 : end - 1;
        cv0 = *(const uint4*)(xl + (size_t)csrc[beg] * 512 + c0);
        ce0 = ce[beg];
        cv1 = *(const uint4*)(xl + (size_t)csrc[i1] * 512 + c0);
        ce1 = ce[i1];
    }
    int i = beg;
    for (; i + 1 < end; i += 2) {
        uint4 a0 = cv0, a1 = cv1;
        float2 d0 = ce0, d1 = ce1;
        int q0 = i + 2, q1 = i + 3;
        q0 = (q0 < end) ? q0 : end - 1;
        q1 = (q1 < end) ? q1 : end - 1;
        cv0 = *(const uint4*)(xl + (size_t)csrc[q0] * 512 + c0);
        ce0 = ce[q0];
        cv1 = *(const uint4*)(xl + (size_t)csrc[q1] * 512 + c0);
        ce1 = ce[q1];
        float lv0[8], lv1[8];
        unpk8(a0, lv0);
        unpk8(a1, lv1);
        float p0 = 0.f, p1 = 0.f;
#pragma unroll
        for (int j = 0; j < 8; j++) {
            float v0 = lv0[j] + rv[j] + d0.x * wv0[j] + d0.y * wv1[j];
            float v1 = lv1[j] + rv[j] + d1.x * wv0[j] + d1.y * wv1[j];
            v0 = fmaxf(v0, 0.2f * v0);   // leaky_relu(0.2)
            v1 = fmaxf(v1, 0.2f * v1);
            p0 += av[j] * v0;
            p1 += av[j] * v1;
        }
        p0 += __shfl_xor(p0, 1);  p1 += __shfl_xor(p1, 1);
        p0 += __shfl_xor(p0, 2);  p1 += __shfl_xor(p1, 2);
        p0 += __shfl_xor(p0, 4);  p1 += __shfl_xor(p1, 4);
        p0 += __shfl_xor(p0, 8);  p1 += __shfl_xor(p1, 8);
        float w0 = __expf(fminf(p0, 60.f));
        float w1 = __expf(fminf(p1, 60.f));
        l += w0 + w1;
#pragma unroll
        for (int j = 0; j < 8; j++)
            acc[j] += w0 * lv0[j] + w1 * lv1[j];
    }
    if (i < end) {
        float lv[8];
        unpk8(cv0, lv);
        float p = 0.f;
#pragma unroll
        for (int j = 0; j < 8; j++) {
            float v = lv[j] + rv[j] + ce0.x * wv0[j] + ce0.y * wv1[j];
            v = fmaxf(v, 0.2f * v);
            p += av[j] * v;
        }
        p += __shfl_xor(p, 1);
        p += __shfl_xor(p, 2);
        p += __shfl_xor(p, 4);
        p += __shfl_xor(p, 8);
        float w = __expf(fminf(p, 60.f));
        l += w;
#pragma unroll
        for (int j = 0; j < 8; j++) acc[j] += w * lv[j];
    }
    float inv = 1.f / (l + 1e-16f);
    const float* bb = bias + c0;
    float4 b0 = *(const float4*)bb, b1 = *(const float4*)(bb + 4);
    float* o = out + (size_t)n * 512 + c0;
    *(float4*)o = make_float4(acc[0] * inv + b0.x, acc[1] * inv + b0.y,
                              acc[2] * inv + b0.z, acc[3] * inv + b0.w);
    *(float4*)(o + 4) = make_float4(acc[4] * inv + b1.x, acc[5] * inv + b1.y,
                                    acc[6] * inv + b1.z, acc[7] * inv + b1.w);
}

// ---------- BN stats (pure atomics, no fence) ----------
__global__ __launch_bounds__(256) void k_bnstat(const float* __restrict__ x,
                                                double* __restrict__ sum,
                                                double* __restrict__ sumsq) {
    int t = threadIdx.x;
    int r0 = blockIdx.x * 64;
    float s0 = 0.f, s1 = 0.f, q0 = 0.f, q1 = 0.f;
    for (int r = r0; r < r0 + 64; r++) {
        float v0 = x[(size_t)r * 512 + t];
        float v1 = x[(size_t)r * 512 + t + 256];
        s0 += v0; q0 += v0 * v0;
        s1 += v1; q1 += v1 * v1;
    }
    atomicAdd(sum + t, (double)s0);
    atomicAdd(sum + t + 256, (double)s1);
    atomicAdd(sumsq + t, (double)q0);
    atomicAdd(sumsq + t + 256, (double)q1);
}

__global__ void k_bnfin(const double* __restrict__ sum, const double* __restrict__ sumsq,
                        const float* __restrict__ g, float* __restrict__ mean,
                        float* __restrict__ scale) {
    int c = blockIdx.x * 256 + threadIdx.x;
    if (c < 512) {
        double mu = sum[c] * (1.0 / NN);
        double var = sumsq[c] * (1.0 / NN) - mu * mu;
        mean[c] = (float)mu;
        scale[c] = g[c] * rsqrtf((float)var + 1e-5f);
    }
}

// ---------- BN apply + ELU + optional residual, float4-vectorized ----------
__global__ void k_bnapply(const float* __restrict__ v, const float* __restrict__ resid,
                          const float* __restrict__ mean, const float* __restrict__ scale,
                          const float* __restrict__ beta, float* __restrict__ out,
                          unsigned short* __restrict__ outb) {
    int i = (blockIdx.x * 256 + threadIdx.x) << 2;
    int c = i & 511;
    float4 vv = *(const float4*)(v + i);
    float4 mm = *(const float4*)(mean + c);
    float4 ss = *(const float4*)(scale + c);
    float4 be = *(const float4*)(beta + c);
    float y0 = (vv.x - mm.x) * ss.x + be.x;
    float y1 = (vv.y - mm.y) * ss.y + be.y;
    float y2 = (vv.z - mm.z) * ss.z + be.z;
    float y3 = (vv.w - mm.w) * ss.w + be.w;
    y0 = y0 > 0.f ? y0 : expm1f(y0);
    y1 = y1 > 0.f ? y1 : expm1f(y1);
    y2 = y2 > 0.f ? y2 : expm1f(y2);
    y3 = y3 > 0.f ? y3 : expm1f(y3);
    if (resid) {
        float4 rr = *(const float4*)(resid + i);
        y0 += rr.x; y1 += rr.y; y2 += rr.z; y3 += rr.w;
    }
    *(float4*)(out + i) = make_float4(y0, y1, y2, y3);
    if (outb) {
        ushort4 o;
        o.x = f2bf(y0); o.y = f2bf(y1); o.z = f2bf(y2); o.w = f2bf(y3);
        *(ushort4*)(outb + i) = o;
    }
}

// ---------- pooling ----------
__global__ __launch_bounds__(256) void k_pool(const float* __restrict__ x,
                                              const int* __restrict__ batch,
                                              float* __restrict__ pooled) {
    __shared__ float lacc[NG][512];
    int t = threadIdx.x;
    for (int i = t; i < NG * 512; i += 256) ((float*)lacc)[i] = 0.f;
    __syncthreads();
    int r0 = blockIdx.x * 64;
    for (int r = r0; r < r0 + 64; r++) {
        int g = batch[r];
        lacc[g][t] += x[(size_t)r * 512 + t];
        lacc[g][t + 256] += x[(size_t)r * 512 + t + 256];
    }
    __syncthreads();
    int gmin = batch[r0], gmax = batch[r0 + 63];
    for (int g = gmin; g <= gmax; g++)
        for (int i = t; i < 512; i += 256)
            atomicAdd(&pooled[g * 512 + i], lacc[g][i]);
}

// ---------- MLP head ----------
__global__ __launch_bounds__(256) void k_mlp1(const float* __restrict__ pooled,
                                              const int* __restrict__ gcnt,
                                              const float* __restrict__ W1,
                                              const float* __restrict__ b1,
                                              float* __restrict__ h1) {
    int g = blockIdx.x, o = threadIdx.x;
    float dot = 0.f;
    for (int c = 0; c < 512; c++) dot += pooled[g * 512 + c] * W1[c * 256 + o];
    float s = dot / (float)gcnt[g] + b1[o];
    h1[g * 256 + o] = fmaxf(s, 0.f);
}

// mlp2 + classifier fused: block = one graph
__global__ __launch_bounds__(256) void k_head(const float* __restrict__ h1,
                                              const float* __restrict__ W2,
                                              const float* __restrict__ b2,
                                              const float* __restrict__ clsW,
                                              const float* __restrict__ clsb,
                                              float* __restrict__ outp) {
    __shared__ float es[256];
    int g = blockIdx.x, o = threadIdx.x;
    float s = b2[o];
    for (int c = 0; c < 256; c++) s += h1[g * 256 + c] * W2[c * 256 + o];
    outp[NG * 12 + g * 256 + o] = s;  // emb
    es[o] = s;
    __syncthreads();
    if (o < 12) {
        float lg = clsb[o];
        for (int c = 0; c < 256; c++) lg += es[c] * clsW[c * 12 + o];
        outp[g * 12 + o] = lg;  // logits
    }
}

extern "C" void kernel_launch(void* const* d_in, const int* in_sizes, int n_in,
                              void* d_out, int out_size, void* d_ws, size_t ws_size,
                              hipStream_t stream) {
    const float* x     = (const float*)d_in[0];
    const float* ea    = (const float*)d_in[1];
    const int*   ei    = (const int*)d_in[2];
    const int*   batch = (const int*)d_in[3];
    const int* src = ei;
    const int* dst = ei + NE;

    float* base = (float*)d_ws;
    size_t off = 0;
    auto alloc = [&](size_t n) -> float* {   // n = FLOAT count
        float* p = base + off;
        off += (n + 255) & ~(size_t)255;
        return p;
    };
    unsigned short* xl  = (unsigned short*)alloc((size_t)NN * 256);  // [NN,512] bf16
    unsigned short* xr  = (unsigned short*)alloc((size_t)NN * 256);
    float*    bufA  = alloc((size_t)NN * 512);
    float*    bufB  = alloc((size_t)NN * 512);
    unsigned short* Xb  = (unsigned short*)alloc((size_t)NN * 256);  // [NN,512] bf16
    unsigned short* Wt2 = (unsigned short*)alloc(512 * 1024 / 2);    // [1024,512] bf16
    unsigned short* Wt3 = (unsigned short*)alloc(512 * 1024 / 2);
    int*      cnt   = (int*)alloc(NN);
    int*      rp    = (int*)alloc(NN + 1);
    int*      offp  = (int*)alloc(NN);
    int*      csrc  = (int*)alloc(NE);
    float2*   ce    = (float2*)alloc((size_t)NE * 2);
    double*   bsum3 = (double*)alloc(3 * 2048);  // 3 layers x (bsum[512] | bsq[512]) doubles
    float*    bmean = alloc(512);
    float*    bscale= alloc(512);
    float*    pooled= alloc(NG * 512);
    int*      gcnt  = (int*)alloc(NG);
    float*    h1    = alloc(NG * 256);
    float*    outp  = (float*)d_out;  // [0,96): logits, [96,2144): emb

    hipMemsetAsync(cnt, 0, NN * sizeof(int), stream);
    hipMemsetAsync(bsum3, 0, 3 * 2048 * sizeof(float), stream);  // all 3 layers' stats
    k_hist<<<NE / 256, 256, 0, stream>>>(dst, cnt);
    k_scan<<<1, 1024, 0, stream>>>(cnt, rp, offp, batch, gcnt);
    k_fill<<<NE / 256, 256, 0, stream>>>(dst, src, ea, offp, csrc, ce);
    k_wt4<<<256, 256, 0, stream>>>((const float*)d_in[11], (const float*)d_in[12],
                                   (const float*)d_in[18], (const float*)d_in[19], Wt2, Wt3);

    float* X = bufA;
    float* Y = bufB;
    for (int l = 0; l < 3; l++) {
        const float* Wl  = (const float*)d_in[4 + l * 7 + 0];
        const float* Wr  = (const float*)d_in[4 + l * 7 + 1];
        const float* We  = (const float*)d_in[4 + l * 7 + 2];
        const float* att = (const float*)d_in[4 + l * 7 + 3];
        const float* cb  = (const float*)d_in[4 + l * 7 + 4];
        const float* bg  = (const float*)d_in[4 + l * 7 + 5];
        const float* bb  = (const float*)d_in[4 + l * 7 + 6];

        if (l == 0) {
            k_lin1<<<NN / 4, 256, 0, stream>>>(x, Wl, Wr, xl, xr);
        } else {
            k_gemm_bf16<<<1024, 256, 0, stream>>>(Xb, (l == 1) ? Wt2 : Wt3, xl, xr);
        }
        k_attn<<<NN / 4, 256, 0, stream>>>(xl, xr, rp, csrc, ce, We, att, cb, Y);

        double* bsum = bsum3 + l * 1024;
        double* bsq  = bsum + 512;
        k_bnstat<<<256, 256, 0, stream>>>(Y, bsum, bsq);
        k_bnfin<<<2, 256, 0, stream>>>(bsum, bsq, bg, bmean, bscale);
        k_bnapply<<<(size_t)NN * 512 / 1024, 256, 0, stream>>>(
            Y, (l == 0) ? nullptr : X, bmean, bscale, bb, Y,
            (l < 2) ? Xb : nullptr);

        float* tmp = X; X = Y; Y = tmp;
    }

    hipMemsetAsync(pooled, 0, NG * 512 * sizeof(float), stream);
    k_pool<<<NN / 64, 256, 0, stream>>>(X, batch, pooled);

    const float* geW1 = (const float*)d_in[25];
    const float* geb1 = (const float*)d_in[26];
    const float* geW2 = (const float*)d_in[27];
    const float* geb2 = (const float*)d_in[28];
    const float* clsW = (const float*)d_in[29];
    const float* clsb = (const float*)d_in[30];

    k_mlp1<<<NG, 256, 0, stream>>>(pooled, gcnt, geW1, geb1, h1);
    k_head<<<NG, 256, 0, stream>>>(h1, geW2, geb2, clsW, clsb, outp);
}

// Round 14
// 518.294 us; speedup vs baseline: 1.1156x; 1.0113x over previous
//
#include <hip/hip_runtime.h>
#include <math.h>

#define NN    16384
#define NE    262144
#define NHEAD 4
#define HC    512
#define NG    8

typedef __bf16 bf16x8 __attribute__((ext_vector_type(8)));
typedef float floatx4 __attribute__((ext_vector_type(4)));

__device__ __forceinline__ unsigned short f2bf(float f) {
    union { float f; unsigned u; } v{f};
    unsigned r = v.u + 0x7FFFu + ((v.u >> 16) & 1u);  // RNE
    return (unsigned short)(r >> 16);
}

__device__ __forceinline__ void unpk8(uint4 v, float* f) {
    f[0] = __uint_as_float(v.x << 16); f[1] = __uint_as_float(v.x & 0xFFFF0000u);
    f[2] = __uint_as_float(v.y << 16); f[3] = __uint_as_float(v.y & 0xFFFF0000u);
    f[4] = __uint_as_float(v.z << 16); f[5] = __uint_as_float(v.z & 0xFFFF0000u);
    f[6] = __uint_as_float(v.w << 16); f[7] = __uint_as_float(v.w & 0xFFFF0000u);
}

// ---------- CSR build ----------
__global__ void k_hist(const int* __restrict__ dst, int* __restrict__ cnt) {
    int e = blockIdx.x * 256 + threadIdx.x;
    if (e < NE) atomicAdd(&cnt[dst[e]], 1);
}

__global__ __launch_bounds__(1024) void k_scan(const int* __restrict__ cnt,
                                               int* __restrict__ rp,
                                               int* __restrict__ offp,
                                               const int* __restrict__ batch,
                                               int* __restrict__ gcnt) {
    __shared__ int part[1024];
    int t = threadIdx.x;
    if (t < NG) {  // fused gcnt: batch sorted -> binary searches
        int lb[2];
#pragma unroll
        for (int q = 0; q < 2; q++) {
            int target = t + q;
            int lo = 0, hi = NN;
            while (lo < hi) {
                int mid = (lo + hi) >> 1;
                if (batch[mid] < target) lo = mid + 1; else hi = mid;
            }
            lb[q] = lo;
        }
        gcnt[t] = lb[1] - lb[0];
    }
    int base = t * 16;
    int loc[16];
    int s = 0;
#pragma unroll
    for (int i = 0; i < 16; i++) { loc[i] = s; s += cnt[base + i]; }
    part[t] = s;
    __syncthreads();
    for (int off = 1; off < 1024; off <<= 1) {
        int v = 0;
        if (t >= off) v = part[t - off];
        __syncthreads();
        if (t >= off) part[t] += v;
        __syncthreads();
    }
    int excl = (t == 0) ? 0 : part[t - 1];
#pragma unroll
    for (int i = 0; i < 16; i++) {
        int r = excl + loc[i];
        rp[base + i] = r;
        offp[base + i] = r;
    }
    if (t == 1023) rp[NN] = excl + s;
}

__global__ void k_fill(const int* __restrict__ dst, const int* __restrict__ src,
                       const float* __restrict__ ea, int* __restrict__ offp,
                       int* __restrict__ csrc, float2* __restrict__ ce) {
    int e = blockIdx.x * 256 + threadIdx.x;
    if (e < NE) {
        int d = dst[e];
        int pos = atomicAdd(&offp[d], 1);
        csrc[pos] = src[e];
        ce[pos] = *(const float2*)(ea + 2 * (size_t)e);
    }
}

// ---------- layer-1 linear (K=5), bf16 out, vectorized ----------
__global__ __launch_bounds__(256) void k_lin1(const float* __restrict__ x,
                                              const float* __restrict__ Wl,
                                              const float* __restrict__ Wr,
                                              unsigned short* __restrict__ xl,
                                              unsigned short* __restrict__ xr) {
    int n = blockIdx.x * 4 + (threadIdx.x >> 6);
    int lane = threadIdx.x & 63;
    int j0 = lane << 3;
    float xs[5];
#pragma unroll
    for (int k = 0; k < 5; k++) xs[k] = x[n * 5 + k];
    float al[8] = {}, ar[8] = {};
#pragma unroll
    for (int k = 0; k < 5; k++) {
        float4 wl0 = *(const float4*)(Wl + k * 512 + j0);
        float4 wl1 = *(const float4*)(Wl + k * 512 + j0 + 4);
        float4 wr0 = *(const float4*)(Wr + k * 512 + j0);
        float4 wr1 = *(const float4*)(Wr + k * 512 + j0 + 4);
        al[0] += xs[k] * wl0.x; al[1] += xs[k] * wl0.y; al[2] += xs[k] * wl0.z; al[3] += xs[k] * wl0.w;
        al[4] += xs[k] * wl1.x; al[5] += xs[k] * wl1.y; al[6] += xs[k] * wl1.z; al[7] += xs[k] * wl1.w;
        ar[0] += xs[k] * wr0.x; ar[1] += xs[k] * wr0.y; ar[2] += xs[k] * wr0.z; ar[3] += xs[k] * wr0.w;
        ar[4] += xs[k] * wr1.x; ar[5] += xs[k] * wr1.y; ar[6] += xs[k] * wr1.z; ar[7] += xs[k] * wr1.w;
    }
    ushort4 o0, o1;
    o0.x = f2bf(al[0]); o0.y = f2bf(al[1]); o0.z = f2bf(al[2]); o0.w = f2bf(al[3]);
    o1.x = f2bf(al[4]); o1.y = f2bf(al[5]); o1.z = f2bf(al[6]); o1.w = f2bf(al[7]);
    *(ushort4*)(xl + (size_t)n * 512 + j0) = o0;
    *(ushort4*)(xl + (size_t)n * 512 + j0 + 4) = o1;
    o0.x = f2bf(ar[0]); o0.y = f2bf(ar[1]); o0.z = f2bf(ar[2]); o0.w = f2bf(ar[3]);
    o1.x = f2bf(ar[4]); o1.y = f2bf(ar[5]); o1.z = f2bf(ar[6]); o1.w = f2bf(ar[7]);
    *(ushort4*)(xr + (size_t)n * 512 + j0) = o0;
    *(ushort4*)(xr + (size_t)n * 512 + j0 + 4) = o1;
}

// ---------- 4 weight transposes in one dispatch ----------
__global__ __launch_bounds__(256) void k_wt4(const float* __restrict__ W0,
                                             const float* __restrict__ W1,
                                             const float* __restrict__ W2,
                                             const float* __restrict__ W3,
                                             unsigned short* __restrict__ Wt2,
                                             unsigned short* __restrict__ Wt3) {
    __shared__ float tile[64][65];
    int bid = blockIdx.x;
    int mat = bid >> 6, sub = bid & 63;
    const float* W = (mat == 0) ? W0 : (mat == 1) ? W1 : (mat == 2) ? W2 : W3;
    unsigned short* Wt = (mat == 0) ? Wt2 : (mat == 1) ? (Wt2 + 512 * 512)
                       : (mat == 2) ? Wt3 : (Wt3 + 512 * 512);
    int n0 = (sub & 7) * 64, k0 = (sub >> 3) * 64;
    int lr = threadIdx.x >> 4;
    int lc = (threadIdx.x & 15) << 2;
    for (int r = lr; r < 64; r += 16) {
        float4 v = *(const float4*)(W + (size_t)(k0 + r) * 512 + n0 + lc);
        tile[r][lc] = v.x; tile[r][lc + 1] = v.y; tile[r][lc + 2] = v.z; tile[r][lc + 3] = v.w;
    }
    __syncthreads();
    for (int r = lr; r < 64; r += 16) {
        ushort4 o;
        o.x = f2bf(tile[lc + 0][r]); o.y = f2bf(tile[lc + 1][r]);
        o.z = f2bf(tile[lc + 2][r]); o.w = f2bf(tile[lc + 3][r]);
        *(ushort4*)(Wt + (size_t)(n0 + r) * 512 + k0 + lc) = o;
    }
}

// ---------- bf16 MFMA GEMM (LDK=72 padded, VGPR staging, XCD-swizzled grid) ----------
#define BM 128
#define BN 128
#define BK 64
#define LDK 72

__global__ __launch_bounds__(256) void k_gemm_bf16(
        const unsigned short* __restrict__ Ab,
        const unsigned short* __restrict__ Bt,
        unsigned short* __restrict__ xl, unsigned short* __restrict__ xr) {
    __shared__ unsigned short As[BM * LDK];
    __shared__ unsigned short Bs[BN * LDK];
    int t = threadIdx.x;
    int bid = blockIdx.x;
    int xcd = bid & 7, r = bid >> 3;
    int m0 = (xcd * 16 + (r & 15)) * BM;
    int n0 = (r >> 4) * BN;
    int wid = t >> 6, lane = t & 63;
    int wm = (wid >> 1) * 64, wn = (wid & 1) * 64;
    int lrow = lane & 15, quad = lane >> 4;
    floatx4 acc[4][4] = {};
    for (int k0 = 0; k0 < 512; k0 += BK) {
        __syncthreads();
#pragma unroll
        for (int it = 0; it < 4; it++) {
            int cid = it * 256 + t;
            int row = cid >> 3, ch = cid & 7;
            uint4 va = *(const uint4*)(Ab + (size_t)(m0 + row) * 512 + k0 + ch * 8);
            *(uint4*)&As[row * LDK + ch * 8] = va;
            uint4 vb = *(const uint4*)(Bt + (size_t)(n0 + row) * 512 + k0 + ch * 8);
            *(uint4*)&Bs[row * LDK + ch * 8] = vb;
        }
        __syncthreads();
#pragma unroll
        for (int ko = 0; ko < 2; ko++) {
            bf16x8 af[4], bfr[4];
#pragma unroll
            for (int i = 0; i < 4; i++) {
                af[i]  = *(const bf16x8*)&As[(wm + i * 16 + lrow) * LDK + ko * 32 + quad * 8];
                bfr[i] = *(const bf16x8*)&Bs[(wn + i * 16 + lrow) * LDK + ko * 32 + quad * 8];
            }
#pragma unroll
            for (int i = 0; i < 4; i++)
#pragma unroll
                for (int j = 0; j < 4; j++)
                    acc[i][j] = __builtin_amdgcn_mfma_f32_16x16x32_bf16(af[i], bfr[j], acc[i][j], 0, 0, 0);
        }
    }
#pragma unroll
    for (int i = 0; i < 4; i++) {
        int row = m0 + wm + i * 16 + quad * 4;
#pragma unroll
        for (int j = 0; j < 4; j++) {
            int col = n0 + wn + j * 16 + lrow;
            unsigned short* dstp = (col < 512) ? (xl + (size_t)row * 512 + col)
                                               : (xr + (size_t)row * 512 + (col - 512));
#pragma unroll
            for (int rr = 0; rr < 4; rr++) dstp[(size_t)rr * 512] = f2bf(acc[i][j][rr]);
        }
    }
}

// ---------- fused GATv2 edge phase: 2-wide edges, no-max softmax ----------
__global__ __launch_bounds__(256) void k_attn(
        const unsigned short* __restrict__ xl, const unsigned short* __restrict__ xr,
        const int* __restrict__ rp, const int* __restrict__ csrc,
        const float2* __restrict__ ce, const float* __restrict__ We,
        const float* __restrict__ att, const float* __restrict__ bias,
        float* __restrict__ out) {
    int n = blockIdx.x * 4 + (threadIdx.x >> 6);
    int lane = threadIdx.x & 63;
    int c0 = lane << 3;
    float wv0[8], wv1[8], av[8], rv[8];
    {
        float4 a = *(const float4*)(We + c0), b = *(const float4*)(We + c0 + 4);
        wv0[0]=a.x; wv0[1]=a.y; wv0[2]=a.z; wv0[3]=a.w; wv0[4]=b.x; wv0[5]=b.y; wv0[6]=b.z; wv0[7]=b.w;
        a = *(const float4*)(We + 512 + c0); b = *(const float4*)(We + 512 + c0 + 4);
        wv1[0]=a.x; wv1[1]=a.y; wv1[2]=a.z; wv1[3]=a.w; wv1[4]=b.x; wv1[5]=b.y; wv1[6]=b.z; wv1[7]=b.w;
        a = *(const float4*)(att + c0); b = *(const float4*)(att + c0 + 4);
        av[0]=a.x; av[1]=a.y; av[2]=a.z; av[3]=a.w; av[4]=b.x; av[5]=b.y; av[6]=b.z; av[7]=b.w;
        uint4 vr = *(const uint4*)(xr + (size_t)n * 512 + c0);
        unpk8(vr, rv);
    }
    float l = 0.f;
    float acc[8] = {0.f, 0.f, 0.f, 0.f, 0.f, 0.f, 0.f, 0.f};
    int beg = rp[n], end = rp[n + 1];
    uint4 cv0 = {}, cv1 = {};
    float2 ce0 = {}, ce1 = {};
    if (beg < end) {
        int i1 = (beg + 1 < end) ? beg + 1 : end - 1;
        cv0 = *(const uint4*)(xl + (size_t)csrc[beg] * 512 + c0);
        ce0 = ce[beg];
        cv1 = *(const uint4*)(xl + (size_t)csrc[i1] * 512 + c0);
        ce1 = ce[i1];
    }
    int i = beg;
    for (; i + 1 < end; i += 2) {
        uint4 a0 = cv0, a1 = cv1;
        float2 d0 = ce0, d1 = ce1;
        int q0 = i + 2, q1 = i + 3;
        q0 = (q0 < end) ? q0 : end - 1;
        q1 = (q1 < end) ? q1 : end - 1;
        cv0 = *(const uint4*)(xl + (size_t)csrc[q0] * 512 + c0);
        ce0 = ce[q0];
        cv1 = *(const uint4*)(xl + (size_t)csrc[q1] * 512 + c0);
        ce1 = ce[q1];
        float lv0[8], lv1[8];
        unpk8(a0, lv0);
        unpk8(a1, lv1);
        float p0 = 0.f, p1 = 0.f;
#pragma unroll
        for (int j = 0; j < 8; j++) {
            float v0 = lv0[j] + rv[j] + d0.x * wv0[j] + d0.y * wv1[j];
            float v1 = lv1[j] + rv[j] + d1.x * wv0[j] + d1.y * wv1[j];
            v0 = fmaxf(v0, 0.2f * v0);   // leaky_relu(0.2)
            v1 = fmaxf(v1, 0.2f * v1);
            p0 += av[j] * v0;
            p1 += av[j] * v1;
        }
        p0 += __shfl_xor(p0, 1);  p1 += __shfl_xor(p1, 1);
        p0 += __shfl_xor(p0, 2);  p1 += __shfl_xor(p1, 2);
        p0 += __shfl_xor(p0, 4);  p1 += __shfl_xor(p1, 4);
        p0 += __shfl_xor(p0, 8);  p1 += __shfl_xor(p1, 8);
        float w0 = __expf(fminf(p0, 60.f));
        float w1 = __expf(fminf(p1, 60.f));
        l += w0 + w1;
#pragma unroll
        for (int j = 0; j < 8; j++)
            acc[j] += w0 * lv0[j] + w1 * lv1[j];
    }
    if (i < end) {
        float lv[8];
        unpk8(cv0, lv);
        float p = 0.f;
#pragma unroll
        for (int j = 0; j < 8; j++) {
            float v = lv[j] + rv[j] + ce0.x * wv0[j] + ce0.y * wv1[j];
            v = fmaxf(v, 0.2f * v);
            p += av[j] * v;
        }
        p += __shfl_xor(p, 1);
        p += __shfl_xor(p, 2);
        p += __shfl_xor(p, 4);
        p += __shfl_xor(p, 8);
        float w = __expf(fminf(p, 60.f));
        l += w;
#pragma unroll
        for (int j = 0; j < 8; j++) acc[j] += w * lv[j];
    }
    float inv = 1.f / (l + 1e-16f);
    const float* bb = bias + c0;
    float4 b0 = *(const float4*)bb, b1 = *(const float4*)(bb + 4);
    float* o = out + (size_t)n * 512 + c0;
    *(float4*)o = make_float4(acc[0] * inv + b0.x, acc[1] * inv + b0.y,
                              acc[2] * inv + b0.z, acc[3] * inv + b0.w);
    *(float4*)(o + 4) = make_float4(acc[4] * inv + b1.x, acc[5] * inv + b1.y,
                                    acc[6] * inv + b1.z, acc[7] * inv + b1.w);
}

// ---------- BN stats (pure atomics, no fence) ----------
__global__ __launch_bounds__(256) void k_bnstat(const float* __restrict__ x,
                                                double* __restrict__ sum,
                                                double* __restrict__ sumsq) {
    int t = threadIdx.x;
    int r0 = blockIdx.x * 64;
    float s0 = 0.f, s1 = 0.f, q0 = 0.f, q1 = 0.f;
    for (int r = r0; r < r0 + 64; r++) {
        float v0 = x[(size_t)r * 512 + t];
        float v1 = x[(size_t)r * 512 + t + 256];
        s0 += v0; q0 += v0 * v0;
        s1 += v1; q1 += v1 * v1;
    }
    atomicAdd(sum + t, (double)s0);
    atomicAdd(sum + t + 256, (double)s1);
    atomicAdd(sumsq + t, (double)q0);
    atomicAdd(sumsq + t + 256, (double)q1);
}

// ---------- BN finalize+apply + ELU + optional residual (bnfin folded in) ----------
__global__ void k_bnapply(const float* __restrict__ v, const float* __restrict__ resid,
                          const double* __restrict__ sum, const double* __restrict__ sumsq,
                          const float* __restrict__ g, const float* __restrict__ beta,
                          float* __restrict__ out, unsigned short* __restrict__ outb) {
    int i = (blockIdx.x * 256 + threadIdx.x) << 2;
    int c = i & 511;
    float4 vv = *(const float4*)(v + i);
    double2 s01 = *(const double2*)(sum + c);
    double2 s23 = *(const double2*)(sum + c + 2);
    double2 q01 = *(const double2*)(sumsq + c);
    double2 q23 = *(const double2*)(sumsq + c + 2);
    float4 gg = *(const float4*)(g + c);
    float4 be = *(const float4*)(beta + c);
    const double invN = 1.0 / NN;
    double mu0 = s01.x * invN, mu1 = s01.y * invN, mu2 = s23.x * invN, mu3 = s23.y * invN;
    float sc0 = gg.x * rsqrtf((float)(q01.x * invN - mu0 * mu0) + 1e-5f);
    float sc1 = gg.y * rsqrtf((float)(q01.y * invN - mu1 * mu1) + 1e-5f);
    float sc2 = gg.z * rsqrtf((float)(q23.x * invN - mu2 * mu2) + 1e-5f);
    float sc3 = gg.w * rsqrtf((float)(q23.y * invN - mu3 * mu3) + 1e-5f);
    float y0 = (vv.x - (float)mu0) * sc0 + be.x;
    float y1 = (vv.y - (float)mu1) * sc1 + be.y;
    float y2 = (vv.z - (float)mu2) * sc2 + be.z;
    float y3 = (vv.w - (float)mu3) * sc3 + be.w;
    y0 = y0 > 0.f ? y0 : expm1f(y0);
    y1 = y1 > 0.f ? y1 : expm1f(y1);
    y2 = y2 > 0.f ? y2 : expm1f(y2);
    y3 = y3 > 0.f ? y3 : expm1f(y3);
    if (resid) {
        float4 rr = *(const float4*)(resid + i);
        y0 += rr.x; y1 += rr.y; y2 += rr.z; y3 += rr.w;
    }
    if (out) *(float4*)(out + i) = make_float4(y0, y1, y2, y3);
    if (outb) {
        ushort4 o;
        o.x = f2bf(y0); o.y = f2bf(y1); o.z = f2bf(y2); o.w = f2bf(y3);
        *(ushort4*)(outb + i) = o;
    }
}

// ---------- pooling (reads bf16 x3) ----------
__global__ __launch_bounds__(256) void k_pool(const unsigned short* __restrict__ xb,
                                              const int* __restrict__ batch,
                                              float* __restrict__ pooled) {
    __shared__ float lacc[NG][512];
    int t = threadIdx.x;
    for (int i = t; i < NG * 512; i += 256) ((float*)lacc)[i] = 0.f;
    __syncthreads();
    int r0 = blockIdx.x * 64;
    for (int r = r0; r < r0 + 64; r++) {
        int g = batch[r];
        lacc[g][t]       += __uint_as_float((unsigned)xb[(size_t)r * 512 + t] << 16);
        lacc[g][t + 256] += __uint_as_float((unsigned)xb[(size_t)r * 512 + t + 256] << 16);
    }
    __syncthreads();
    int gmin = batch[r0], gmax = batch[r0 + 63];
    for (int g = gmin; g <= gmax; g++)
        for (int i = t; i < 512; i += 256)
            atomicAdd(&pooled[g * 512 + i], lacc[g][i]);
}

// ---------- MLP head ----------
__global__ __launch_bounds__(256) void k_mlp1(const float* __restrict__ pooled,
                                              const int* __restrict__ gcnt,
                                              const float* __restrict__ W1,
                                              const float* __restrict__ b1,
                                              float* __restrict__ h1) {
    int g = blockIdx.x, o = threadIdx.x;
    float dot = 0.f;
    for (int c = 0; c < 512; c++) dot += pooled[g * 512 + c] * W1[c * 256 + o];
    float s = dot / (float)gcnt[g] + b1[o];
    h1[g * 256 + o] = fmaxf(s, 0.f);
}

__global__ __launch_bounds__(256) void k_head(const float* __restrict__ h1,
                                              const float* __restrict__ W2,
                                              const float* __restrict__ b2,
                                              const float* __restrict__ clsW,
                                              const float* __restrict__ clsb,
                                              float* __restrict__ outp) {
    __shared__ float es[256];
    int g = blockIdx.x, o = threadIdx.x;
    float s = b2[o];
    for (int c = 0; c < 256; c++) s += h1[g * 256 + c] * W2[c * 256 + o];
    outp[NG * 12 + g * 256 + o] = s;  // emb
    es[o] = s;
    __syncthreads();
    if (o < 12) {
        float lg = clsb[o];
        for (int c = 0; c < 256; c++) lg += es[c] * clsW[c * 12 + o];
        outp[g * 12 + o] = lg;  // logits
    }
}

extern "C" void kernel_launch(void* const* d_in, const int* in_sizes, int n_in,
                              void* d_out, int out_size, void* d_ws, size_t ws_size,
                              hipStream_t stream) {
    const float* x     = (const float*)d_in[0];
    const float* ea    = (const float*)d_in[1];
    const int*   ei    = (const int*)d_in[2];
    const int*   batch = (const int*)d_in[3];
    const int* src = ei;
    const int* dst = ei + NE;

    float* base = (float*)d_ws;
    size_t off = 0;
    auto alloc = [&](size_t n) -> float* {   // n = FLOAT count
        float* p = base + off;
        off += (n + 255) & ~(size_t)255;
        return p;
    };
    unsigned short* xl  = (unsigned short*)alloc((size_t)NN * 256);  // [NN,512] bf16
    unsigned short* xr  = (unsigned short*)alloc((size_t)NN * 256);
    float*    bufA  = alloc((size_t)NN * 512);
    float*    bufB  = alloc((size_t)NN * 512);
    unsigned short* Xb  = (unsigned short*)alloc((size_t)NN * 256);  // [NN,512] bf16
    unsigned short* Wt2 = (unsigned short*)alloc(512 * 1024 / 2);
    unsigned short* Wt3 = (unsigned short*)alloc(512 * 1024 / 2);
    int*      cnt   = (int*)alloc(NN);
    int*      rp    = (int*)alloc(NN + 1);
    int*      offp  = (int*)alloc(NN);
    int*      csrc  = (int*)alloc(NE);
    float2*   ce    = (float2*)alloc((size_t)NE * 2);
    double*   bsum3 = (double*)alloc(3 * 2048);  // 3 layers x (bsum[512]|bsq[512]) doubles
    float*    pooled= alloc(NG * 512);
    int*      gcnt  = (int*)alloc(NG);
    float*    h1    = alloc(NG * 256);
    float*    outp  = (float*)d_out;  // [0,96): logits, [96,2144): emb

    hipMemsetAsync(cnt, 0, NN * sizeof(int), stream);
    hipMemsetAsync(bsum3, 0, 3 * 2048 * sizeof(float), stream);
    hipMemsetAsync(pooled, 0, NG * 512 * sizeof(float), stream);  // up-front: overlaps layers
    k_hist<<<NE / 256, 256, 0, stream>>>(dst, cnt);
    k_scan<<<1, 1024, 0, stream>>>(cnt, rp, offp, batch, gcnt);
    k_fill<<<NE / 256, 256, 0, stream>>>(dst, src, ea, offp, csrc, ce);
    k_wt4<<<256, 256, 0, stream>>>((const float*)d_in[11], (const float*)d_in[12],
                                   (const float*)d_in[18], (const float*)d_in[19], Wt2, Wt3);

    float* X = bufA;
    float* Y = bufB;
    for (int l = 0; l < 3; l++) {
        const float* Wl  = (const float*)d_in[4 + l * 7 + 0];
        const float* Wr  = (const float*)d_in[4 + l * 7 + 1];
        const float* We  = (const float*)d_in[4 + l * 7 + 2];
        const float* att = (const float*)d_in[4 + l * 7 + 3];
        const float* cb  = (const float*)d_in[4 + l * 7 + 4];
        const float* bg  = (const float*)d_in[4 + l * 7 + 5];
        const float* bb  = (const float*)d_in[4 + l * 7 + 6];

        if (l == 0) {
            k_lin1<<<NN / 4, 256, 0, stream>>>(x, Wl, Wr, xl, xr);
        } else {
            k_gemm_bf16<<<1024, 256, 0, stream>>>(Xb, (l == 1) ? Wt2 : Wt3, xl, xr);
        }
        k_attn<<<NN / 4, 256, 0, stream>>>(xl, xr, rp, csrc, ce, We, att, cb, Y);

        double* bsum = bsum3 + l * 1024;
        double* bsq  = bsum + 512;
        k_bnstat<<<256, 256, 0, stream>>>(Y, bsum, bsq);
        // l<2: fp32 out (residual for next layer) + bf16 Xb (GEMM input)
        // l==2: bf16 Xb only (pool input) — skip the 32MB fp32 write
        k_bnapply<<<(size_t)NN * 512 / 1024, 256, 0, stream>>>(
            Y, (l == 0) ? nullptr : X, bsum, bsq, bg, bb,
            (l < 2) ? Y : nullptr, Xb);

        float* tmp = X; X = Y; Y = tmp;
    }

    k_pool<<<NN / 64, 256, 0, stream>>>(Xb, batch, pooled);

    const float* geW1 = (const float*)d_in[25];
    const float* geb1 = (const float*)d_in[26];
    const float* geW2 = (const float*)d_in[27];
    const float* geb2 = (const float*)d_in[28];
    const float* clsW = (const float*)d_in[29];
    const float* clsb = (const float*)d_in[30];

    k_mlp1<<<NG, 256, 0, stream>>>(pooled, gcnt, geW1, geb1, h1);
    k_head<<<NG, 256, 0, stream>>>(h1, geW2, geb2, clsW, clsb, outp);
}